// Round 1
// baseline (10035.239 us; speedup 1.0000x reference)
//
#include <hip/hip_runtime.h>
#include <math.h>

// LinearAttentionLayerOptimized: B=4, T=2048, C=1024, H=16, N=64, L=128, E=1228
// Round 0: correctness-first fp32 implementation.
//   - mu_* shifts folded into bias vectors (tiny precompute kernels)
//   - 128x128x16 LDS-tiled fp32 GEMM with fused epilogues (bias/gelu/sigmoid/decay)
//   - per-(b,h) sequential recurrence kernel, S in LDS, derived vectors on the fly
//   - fused LN+gate kernel

#define BB 4
#define TT 2048
#define CC 1024
#define HH 16
#define NN 64
#define LL 128
#define EE 1228
#define MM (BB*TT)          // 8192 rows
#define DECAY_C_F 0.7408182206817179f

// ---------------- bias folding ----------------
// outb[e] = b1[e] + sum_c mu[c] * W1[c*E + e]
__global__ void fold_bias_E(const float* __restrict__ mu, const float* __restrict__ W1,
                            const float* __restrict__ b1, float* __restrict__ outb,
                            int C, int E) {
    int e = blockIdx.x * blockDim.x + threadIdx.x;
    if (e >= E) return;
    float s = b1[e];
    for (int c = 0; c < C; ++c) s += mu[c] * W1[(size_t)c * E + e];
    outb[e] = s;
}

// ltmp[l] = sum_c mu[c]*A[c*L+l]
__global__ void fold_lora_t(const float* __restrict__ mu, const float* __restrict__ Amat,
                            float* __restrict__ ltmp, int C, int L) {
    int l = blockIdx.x * blockDim.x + threadIdx.x;
    if (l >= L) return;
    float s = 0.f;
    for (int c = 0; c < C; ++c) s += mu[c] * Amat[(size_t)c * L + l];
    ltmp[l] = s;
}

// outc[c] = (bias?bias[c]:0) + sum_l ltmp[l]*Bm[l*C+c]
__global__ void fold_lora_c(const float* __restrict__ ltmp, const float* __restrict__ Bm,
                            const float* __restrict__ bias, float* __restrict__ outc,
                            int L, int C) {
    int c = blockIdx.x * blockDim.x + threadIdx.x;
    if (c >= C) return;
    float s = bias ? bias[c] : 0.f;
    for (int l = 0; l < L; ++l) s += ltmp[l] * Bm[(size_t)l * C + c];
    outc[c] = s;
}

// ---------------- fp32 tiled GEMM ----------------
// C[M,N] = act(A[M,K] @ B[K,N] + bias[N])
// ACT: 0 = none, 1 = exact gelu, 2 = sigmoid, 3 = decay = exp(-DC*sigmoid(tanh(x)))
#define GBM 128
#define GBN 128
#define GBK 16

template<int ACT>
__global__ __launch_bounds__(256) void gemm_f32(const float* __restrict__ A,
                                                const float* __restrict__ B,
                                                const float* __restrict__ bias,
                                                float* __restrict__ Cout,
                                                int M, int N, int K) {
    __shared__ float As[GBK][GBM];   // [k][m] (transposed)
    __shared__ float Bs[GBK][GBN];   // [k][n]
    const int tid = threadIdx.x;
    const int bm = blockIdx.y * GBM;
    const int bn = blockIdx.x * GBN;
    const int tm = (tid >> 4) * 8;   // 0..120
    const int tn = (tid & 15) * 8;

    // A tile load mapping: 2 x float4 per thread
    const int ar = tid >> 2;          // 0..63, + 64
    const int ac = (tid & 3) * 4;     // 0,4,8,12
    // B tile load mapping: 2 x float4 per thread
    const int br = tid >> 5;          // 0..7, + 8
    const int bc = (tid & 31) * 4;    // 0..124

    float acc[8][8];
    #pragma unroll
    for (int i = 0; i < 8; ++i)
        #pragma unroll
        for (int j = 0; j < 8; ++j) acc[i][j] = 0.f;

    const int nkt = (K + GBK - 1) / GBK;
    for (int kt = 0; kt < nkt; ++kt) {
        const int k0 = kt * GBK;
        // ---- load A tile (M assumed multiple of 128; guard K) ----
        #pragma unroll
        for (int rr = 0; rr < 2; ++rr) {
            const int row = ar + rr * 64;
            const int gm = bm + row;
            const int kcol = k0 + ac;
            float4 av;
            if (kcol + 4 <= K) {
                av = *(const float4*)&A[(size_t)gm * K + kcol];
            } else {
                float t0 = (kcol + 0 < K) ? A[(size_t)gm * K + kcol + 0] : 0.f;
                float t1 = (kcol + 1 < K) ? A[(size_t)gm * K + kcol + 1] : 0.f;
                float t2 = (kcol + 2 < K) ? A[(size_t)gm * K + kcol + 2] : 0.f;
                float t3 = (kcol + 3 < K) ? A[(size_t)gm * K + kcol + 3] : 0.f;
                av = make_float4(t0, t1, t2, t3);
            }
            As[ac + 0][row] = av.x;
            As[ac + 1][row] = av.y;
            As[ac + 2][row] = av.z;
            As[ac + 3][row] = av.w;
        }
        // ---- load B tile (guard K rows and N cols) ----
        #pragma unroll
        for (int rr = 0; rr < 2; ++rr) {
            const int kr = br + rr * 8;
            const int krow = k0 + kr;
            const int ncol = bn + bc;
            float4 bv = make_float4(0.f, 0.f, 0.f, 0.f);
            if (krow < K) {
                if (ncol + 4 <= N) {
                    bv = *(const float4*)&B[(size_t)krow * N + ncol];
                } else {
                    if (ncol + 0 < N) bv.x = B[(size_t)krow * N + ncol + 0];
                    if (ncol + 1 < N) bv.y = B[(size_t)krow * N + ncol + 1];
                    if (ncol + 2 < N) bv.z = B[(size_t)krow * N + ncol + 2];
                    if (ncol + 3 < N) bv.w = B[(size_t)krow * N + ncol + 3];
                }
            }
            *(float4*)&Bs[kr][bc] = bv;
        }
        __syncthreads();
        // ---- compute ----
        #pragma unroll
        for (int kk = 0; kk < GBK; ++kk) {
            float4 a0 = *(const float4*)&As[kk][tm];
            float4 a1 = *(const float4*)&As[kk][tm + 4];
            float4 b0 = *(const float4*)&Bs[kk][tn];
            float4 b1 = *(const float4*)&Bs[kk][tn + 4];
            float a[8] = {a0.x, a0.y, a0.z, a0.w, a1.x, a1.y, a1.z, a1.w};
            float b[8] = {b0.x, b0.y, b0.z, b0.w, b1.x, b1.y, b1.z, b1.w};
            #pragma unroll
            for (int i = 0; i < 8; ++i)
                #pragma unroll
                for (int j = 0; j < 8; ++j)
                    acc[i][j] = fmaf(a[i], b[j], acc[i][j]);
        }
        __syncthreads();
    }

    // ---- epilogue ----
    #pragma unroll
    for (int i = 0; i < 8; ++i) {
        const int row = bm + tm + i;
        #pragma unroll
        for (int j = 0; j < 8; ++j) {
            const int col = bn + tn + j;
            if (col < N) {
                float x = acc[i][j] + (bias ? bias[col] : 0.f);
                float y;
                if (ACT == 1) {
                    y = 0.5f * x * (1.0f + erff(x * 0.7071067811865475f));
                } else if (ACT == 2) {
                    y = 1.0f / (1.0f + expf(-x));
                } else if (ACT == 3) {
                    float sg = 1.0f / (1.0f + expf(-tanhf(x)));
                    y = expf(-DECAY_C_F * sg);
                } else {
                    y = x;
                }
                Cout[(size_t)row * N + col] = y;
            }
        }
    }
}

// ---------------- sequential recurrence ----------------
// One block per (b,h). S[j][k] in LDS. Per step:
//   krm = k*rem ; kn = krm/max(||krm||,1e-12) ; rk = k*(1+(a-1)*mix) ; w = a*kn
//   tmp[k] = sum_j w[j]*S[j][k]
//   S[j][k] = d[j]*S[j][k] - kn[j]*tmp[k] + v[j]*rk[k]
//   out[i]  = sum_k S[i][k]*r[k] + (r.rk)*0.2*v[i]*bonus_mult
// NOTE: `outb` may alias `iclr` (read of step t completes before write of step t).
__global__ __launch_bounds__(256) void recurrence_kernel(
    const float* __restrict__ kbuf, const float* __restrict__ vbuf,
    const float* __restrict__ rbuf, const float* __restrict__ dbuf,
    const float* iclr,
    const float* __restrict__ rem_mult, const float* __restrict__ iclr_mix,
    const float* __restrict__ bonus_mult,
    float* outb) {
    const int bh = blockIdx.x;
    const int b = bh >> 4;
    const int h = bh & 15;
    const int tid = threadIdx.x;
    const int lane = tid & 63;
    const int grp = tid >> 6;

    __shared__ float S[NN][NN + 1];
    __shared__ float dv[NN], wv[NN], knv[NN], rkv[NN], vv[NN], rv[NN], bonusv[NN], tmpv[NN];
    __shared__ float tmp4[4][NN];
    __shared__ float outp[4][NN];

    for (int idx = tid; idx < NN * (NN + 1); idx += 256) ((float*)S)[idx] = 0.f;

    const int c = h * NN + lane;
    const float rem = rem_mult[c];
    const float mix = iclr_mix[c];
    const float bon = bonus_mult[c];
    __syncthreads();

    const size_t baseBT = ((size_t)b * TT) * CC + (size_t)h * NN;
    for (int t = 0; t < TT; ++t) {
        const size_t off = baseBT + (size_t)t * CC + lane;
        if (tid < 64) {
            float kx = kbuf[off], ax = iclr[off], dx = dbuf[off];
            float vx = vbuf[off], rx = rbuf[off];
            float krm = kx * rem;
            float ss = krm * krm;
            #pragma unroll
            for (int s = 32; s; s >>= 1) ss += __shfl_xor(ss, s);
            float nrm = fmaxf(sqrtf(ss), 1e-12f);
            float kn = krm / nrm;
            float rk = kx * (1.f + (ax - 1.f) * mix);
            float dot = rx * rk;
            #pragma unroll
            for (int s = 32; s; s >>= 1) dot += __shfl_xor(dot, s);
            dv[lane] = dx; wv[lane] = ax * kn; knv[lane] = kn;
            rkv[lane] = rk; vv[lane] = vx; rv[lane] = rx;
            bonusv[lane] = dot * 0.2f * vx * bon;
        }
        __syncthreads();
        // tmp[k] partials
        {
            float s = 0.f;
            const int j0 = grp * 16;
            #pragma unroll
            for (int j = 0; j < 16; ++j) s = fmaf(wv[j0 + j], S[j0 + j][lane], s);
            tmp4[grp][lane] = s;
        }
        __syncthreads();
        if (tid < 64) tmpv[lane] = tmp4[0][lane] + tmp4[1][lane] + tmp4[2][lane] + tmp4[3][lane];
        __syncthreads();
        // state update
        {
            const float tk = tmpv[lane];
            const float rkk = rkv[lane];
            const int j0 = grp * 16;
            #pragma unroll
            for (int j = 0; j < 16; ++j) {
                const int jj = j0 + j;
                S[jj][lane] = fmaf(dv[jj], S[jj][lane], fmaf(-knv[jj], tk, vv[jj] * rkk));
            }
        }
        __syncthreads();
        // out[i] partials over k
        {
            float s = 0.f;
            const int k0 = grp * 16;
            #pragma unroll
            for (int kk = 0; kk < 16; ++kk) s = fmaf(S[lane][k0 + kk], rv[k0 + kk], s);
            outp[grp][lane] = s;
        }
        __syncthreads();
        if (tid < 64) {
            outb[off] = outp[0][lane] + outp[1][lane] + outp[2][lane] + outp[3][lane] + bonusv[lane];
        }
        __syncthreads();
    }
}

// ---------------- LayerNorm * gate ----------------
__global__ __launch_bounds__(256) void ln_gate_kernel(const float* __restrict__ x,
                                                      const float* __restrict__ gate,
                                                      const float* __restrict__ g,
                                                      const float* __restrict__ bv,
                                                      float* __restrict__ y) {
    const int row = blockIdx.x;
    const float* xr = x + (size_t)row * CC;
    float v[4];
    float s = 0.f;
    #pragma unroll
    for (int j = 0; j < 4; ++j) { v[j] = xr[threadIdx.x + 256 * j]; s += v[j]; }
    __shared__ float red[4], red2[4];
    #pragma unroll
    for (int o = 32; o; o >>= 1) s += __shfl_xor(s, o);
    if ((threadIdx.x & 63) == 0) red[threadIdx.x >> 6] = s;
    __syncthreads();
    const float mean = (red[0] + red[1] + red[2] + red[3]) * (1.f / CC);
    float vs = 0.f;
    #pragma unroll
    for (int j = 0; j < 4; ++j) { float d = v[j] - mean; vs += d * d; }
    #pragma unroll
    for (int o = 32; o; o >>= 1) vs += __shfl_xor(vs, o);
    if ((threadIdx.x & 63) == 0) red2[threadIdx.x >> 6] = vs;
    __syncthreads();
    const float var = (red2[0] + red2[1] + red2[2] + red2[3]) * (1.f / CC);
    const float rstd = rsqrtf(var + 1e-6f);
    #pragma unroll
    for (int j = 0; j < 4; ++j) {
        const int cc = threadIdx.x + 256 * j;
        float o_ = (v[j] - mean) * rstd * g[cc] + bv[cc];
        y[(size_t)row * CC + cc] = o_ * gate[(size_t)row * CC + cc];
    }
}

// ---------------- launch ----------------
extern "C" void kernel_launch(void* const* d_in, const int* in_sizes, int n_in,
                              void* d_out, int out_size, void* d_ws, size_t ws_size,
                              hipStream_t stream) {
    const float* q        = (const float*)d_in[0];
    // d_in[1] keys, d_in[2] values, d_in[3] attn_mask: unused
    const float* mu_r     = (const float*)d_in[4];
    const float* mu_k     = (const float*)d_in[5];
    const float* mu_v     = (const float*)d_in[6];
    const float* mu_g     = (const float*)d_in[7];
    const float* mu_a     = (const float*)d_in[8];
    const float* mu_d     = (const float*)d_in[9];
    const float* dA       = (const float*)d_in[10];
    const float* dB       = (const float*)d_in[11];
    const float* db       = (const float*)d_in[12];
    const float* aA       = (const float*)d_in[13];
    const float* aB       = (const float*)d_in[14];
    const float* ab       = (const float*)d_in[15];
    const float* gA       = (const float*)d_in[16];
    const float* gB       = (const float*)d_in[17];
    const float* rW1      = (const float*)d_in[18];
    const float* rb1      = (const float*)d_in[19];
    const float* rW2      = (const float*)d_in[20];
    const float* rb2      = (const float*)d_in[21];
    const float* kW1      = (const float*)d_in[22];
    const float* kb1      = (const float*)d_in[23];
    const float* kW2      = (const float*)d_in[24];
    const float* kb2      = (const float*)d_in[25];
    const float* vW1      = (const float*)d_in[26];
    const float* vb1      = (const float*)d_in[27];
    const float* vW2      = (const float*)d_in[28];
    const float* vb2      = (const float*)d_in[29];
    const float* oW1      = (const float*)d_in[30];
    const float* ob1      = (const float*)d_in[31];
    const float* oW2      = (const float*)d_in[32];
    const float* ob2      = (const float*)d_in[33];
    const float* rem_mult = (const float*)d_in[34];
    const float* iclr_mix = (const float*)d_in[35];
    const float* bonus_mult = (const float*)d_in[36];
    const float* ln_g     = (const float*)d_in[37];
    const float* ln_b     = (const float*)d_in[38];
    float* out = (float*)d_out;

    // ---- workspace arena (floats) ----
    float* W = (float*)d_ws;
    float* fbr = W + 0;        // E
    float* fbk = W + 2048;     // E
    float* fbv = W + 4096;     // E
    float* cg2 = W + 6144;     // C
    float* ca2 = W + 7168;     // C
    float* cd2 = W + 8192;     // C
    float* lt  = W + 9216;     // L (reused sequentially)
    float* H   = W + 32768;                 // M*E = 10,059,776
    float* tg  = H;                          // M*L (aliases H; LoRA phase only)
    float* ta  = H + 1048576;
    float* td  = H + 2097152;
    const size_t SZ = (size_t)MM * CC;       // 8,388,608
    float* rbuf = W + 32768 + 10059776;
    float* kbuf = rbuf + SZ;
    float* vbuf = kbuf + SZ;
    float* dbuf = vbuf + SZ;
    float* abuf = dbuf + SZ;   // iclr, then recurrence output (aliased), then LN input
    float* gbuf = abuf + SZ;   // gate
    // total: 60,424,192 floats = ~242 MB

    const dim3 blk(256);

    // bias folding
    fold_bias_E<<<dim3((EE + 255) / 256), blk, 0, stream>>>(mu_r, rW1, rb1, fbr, CC, EE);
    fold_bias_E<<<dim3((EE + 255) / 256), blk, 0, stream>>>(mu_k, kW1, kb1, fbk, CC, EE);
    fold_bias_E<<<dim3((EE + 255) / 256), blk, 0, stream>>>(mu_v, vW1, vb1, fbv, CC, EE);
    fold_lora_t<<<dim3(1), dim3(128), 0, stream>>>(mu_g, gA, lt, CC, LL);
    fold_lora_c<<<dim3(4), blk, 0, stream>>>(lt, gB, nullptr, cg2, LL, CC);
    fold_lora_t<<<dim3(1), dim3(128), 0, stream>>>(mu_a, aA, lt, CC, LL);
    fold_lora_c<<<dim3(4), blk, 0, stream>>>(lt, aB, ab, ca2, LL, CC);
    fold_lora_t<<<dim3(1), dim3(128), 0, stream>>>(mu_d, dA, lt, CC, LL);
    fold_lora_c<<<dim3(4), blk, 0, stream>>>(lt, dB, db, cd2, LL, CC);

    // LoRA A stage: t = q @ A   (M x L, K=C)
    gemm_f32<0><<<dim3(1, MM / GBM), blk, 0, stream>>>(q, gA, nullptr, tg, MM, LL, CC);
    gemm_f32<0><<<dim3(1, MM / GBM), blk, 0, stream>>>(q, aA, nullptr, ta, MM, LL, CC);
    gemm_f32<0><<<dim3(1, MM / GBM), blk, 0, stream>>>(q, dA, nullptr, td, MM, LL, CC);
    // LoRA B stage (M x C, K=L) with activations
    gemm_f32<2><<<dim3(CC / GBN, MM / GBM), blk, 0, stream>>>(tg, gB, cg2, gbuf, MM, CC, LL);
    gemm_f32<2><<<dim3(CC / GBN, MM / GBM), blk, 0, stream>>>(ta, aB, ca2, abuf, MM, CC, LL);
    gemm_f32<3><<<dim3(CC / GBN, MM / GBM), blk, 0, stream>>>(td, dB, cd2, dbuf, MM, CC, LL);

    // MLPs: x = gelu(q@W1 + fb) @ W2 + b2
    const dim3 g1((EE + GBN - 1) / GBN, MM / GBM);
    const dim3 g2(CC / GBN, MM / GBM);
    gemm_f32<1><<<g1, blk, 0, stream>>>(q, rW1, fbr, H, MM, EE, CC);
    gemm_f32<0><<<g2, blk, 0, stream>>>(H, rW2, rb2, rbuf, MM, CC, EE);
    gemm_f32<1><<<g1, blk, 0, stream>>>(q, kW1, fbk, H, MM, EE, CC);
    gemm_f32<0><<<g2, blk, 0, stream>>>(H, kW2, kb2, kbuf, MM, CC, EE);
    gemm_f32<1><<<g1, blk, 0, stream>>>(q, vW1, fbv, H, MM, EE, CC);
    gemm_f32<0><<<g2, blk, 0, stream>>>(H, vW2, vb2, vbuf, MM, CC, EE);

    // recurrence (out written into abuf, aliasing iclr)
    recurrence_kernel<<<dim3(BB * HH), blk, 0, stream>>>(kbuf, vbuf, rbuf, dbuf, abuf,
                                                         rem_mult, iclr_mix, bonus_mult, abuf);

    // LN * gate -> y (reuse kbuf)
    ln_gate_kernel<<<dim3(MM), blk, 0, stream>>>(abuf, gbuf, ln_g, ln_b, kbuf);

    // output MLP
    gemm_f32<1><<<g1, blk, 0, stream>>>(kbuf, oW1, ob1, H, MM, EE, CC);
    gemm_f32<0><<<g2, blk, 0, stream>>>(H, oW2, ob2, out, MM, CC, EE);
}

// Round 2
// 5920.997 us; speedup vs baseline: 1.6949x; 1.6949x over previous
//
#include <hip/hip_runtime.h>
#include <hip/hip_bf16.h>
#include <math.h>

// LinearAttentionLayerOptimized: B=4, T=2048, C=1024, H=16, N=64, L=128, E=1228
// Round 1: bf16-MFMA GEMMs + low-latency recurrence (1 barrier/step, state in VGPRs).

#define BB 4
#define TT 2048
#define CC 1024
#define HH 16
#define NN 64
#define LL 128
#define EE 1228
#define EPAD 1280
#define MM (BB*TT)          // 8192 rows
#define DECAY_C_F 0.7408182206817179f

typedef __attribute__((ext_vector_type(8))) short s16x8;
typedef __attribute__((ext_vector_type(4))) float f32x4;

#define GLOAD_LDS16(gp, lp) \
    __builtin_amdgcn_global_load_lds((const __attribute__((address_space(1))) void*)(gp), \
                                     (__attribute__((address_space(3))) void*)(lp), 16, 0, 0)

// ---------------- bias folding (fp32, tiny) ----------------
__global__ void fold_bias_E(const float* __restrict__ mu, const float* __restrict__ W1,
                            const float* __restrict__ b1, float* __restrict__ outb,
                            int C, int E) {
    int e = blockIdx.x * blockDim.x + threadIdx.x;
    if (e >= E) return;
    float s = b1[e];
    for (int c = 0; c < C; ++c) s += mu[c] * W1[(size_t)c * E + e];
    outb[e] = s;
}

__global__ void fold_lora_t(const float* __restrict__ mu, const float* __restrict__ Amat,
                            float* __restrict__ ltmp, int C, int L) {
    int l = blockIdx.x * blockDim.x + threadIdx.x;
    if (l >= L) return;
    float s = 0.f;
    for (int c = 0; c < C; ++c) s += mu[c] * Amat[(size_t)c * L + l];
    ltmp[l] = s;
}

__global__ void fold_lora_c(const float* __restrict__ ltmp, const float* __restrict__ Bm,
                            const float* __restrict__ bias, float* __restrict__ outc,
                            int L, int C) {
    int c = blockIdx.x * blockDim.x + threadIdx.x;
    if (c >= C) return;
    float s = bias ? bias[c] : 0.f;
    for (int l = 0; l < L; ++l) s += ltmp[l] * Bm[(size_t)l * C + c];
    outc[c] = s;
}

// ---------------- cast / transpose-cast ----------------
__global__ void cast_f32_bf16(const float* __restrict__ in, __hip_bfloat16* __restrict__ out, int n4) {
    int i = blockIdx.x * blockDim.x + threadIdx.x;
    if (i >= n4) return;
    float4 v = ((const float4*)in)[i];
    __hip_bfloat16 o[4] = {__float2bfloat16(v.x), __float2bfloat16(v.y),
                           __float2bfloat16(v.z), __float2bfloat16(v.w)};
    *(ulong1*)&out[i * 4] = *(ulong1*)o;
}

// out[c*Rpad + r] = (r<Rin && c<Cin) ? in[r*Cin + c] : 0, for c<Cpad, r<Rpad
__global__ void transpose_cast(const float* __restrict__ in, __hip_bfloat16* __restrict__ outT,
                               int Rin, int Cin, int Rpad, int Cpad) {
    __shared__ float t[32][33];
    const int r0 = blockIdx.x * 32, c0 = blockIdx.y * 32;
    const int tx = threadIdx.x, ty = threadIdx.y;   // 32 x 8
    #pragma unroll
    for (int j = 0; j < 4; ++j) {
        int r = r0 + ty + j * 8, c = c0 + tx;
        t[ty + j * 8][tx] = (r < Rin && c < Cin) ? in[(size_t)r * Cin + c] : 0.f;
    }
    __syncthreads();
    #pragma unroll
    for (int j = 0; j < 4; ++j) {
        int c = c0 + ty + j * 8, r = r0 + tx;
        if (c < Cpad && r < Rpad) outT[(size_t)c * Rpad + r] = __float2bfloat16(t[tx][ty + j * 8]);
    }
}

// ---------------- bf16 MFMA GEMM ----------------
// C[M,N] = act(A[M,K] @ Bt[N,K]^T + bias[N])
// A: bf16 [M][ldA], Bt: bf16 [Npad][ldB] (row n = column n of B), K mult of 32, M mult of 128.
// ACT: 0 none, 1 exact gelu, 2 sigmoid, 3 decay. OBF: bf16 output. PADZ: store 0 for col>=N.
template<int ACT, int OBF, int PADZ>
__global__ __launch_bounds__(256) void gemm_mfma(const __hip_bfloat16* __restrict__ A,
                                                 const __hip_bfloat16* __restrict__ Bt,
                                                 const float* __restrict__ bias,
                                                 void* __restrict__ Cptr,
                                                 int M, int N, int K,
                                                 int ldA, int ldB, int ldC) {
    __shared__ __hip_bfloat16 As[128 * 32];
    __shared__ __hip_bfloat16 Bs[128 * 32];
    const int tid = threadIdx.x;
    const int wid = tid >> 6, lane = tid & 63;
    const int wm = wid >> 1, wn = wid & 1;
    const int bm = blockIdx.y * 128, bn = blockIdx.x * 128;

    // staging mapping: region (wid*2+i)*1024 bytes, lane writes 16B at +lane*16.
    // LDS(r, c) holds global k-chunk c ^ ((r>>1)&3) of row r  (chunk = 8 bf16 = 16B).
    const __hip_bfloat16* srcA[2];
    const __hip_bfloat16* srcB[2];
    #pragma unroll
    for (int i = 0; i < 2; ++i) {
        int off = (wid * 2 + i) * 1024 + lane * 16;
        int r = off >> 6;
        int c = (off >> 4) & 3;
        int cs = c ^ ((r >> 1) & 3);
        srcA[i] = A  + (size_t)(bm + r) * ldA + cs * 8;
        srcB[i] = Bt + (size_t)(bn + r) * ldB + cs * 8;
    }

    f32x4 acc[4][4];
    #pragma unroll
    for (int i = 0; i < 4; ++i)
        #pragma unroll
        for (int j = 0; j < 4; ++j) acc[i][j] = (f32x4){0.f, 0.f, 0.f, 0.f};

    for (int k0 = 0; k0 < K; k0 += 32) {
        #pragma unroll
        for (int i = 0; i < 2; ++i) {
            GLOAD_LDS16(srcA[i] + k0, (char*)As + (wid * 2 + i) * 1024);
            GLOAD_LDS16(srcB[i] + k0, (char*)Bs + (wid * 2 + i) * 1024);
        }
        __syncthreads();
        s16x8 af[4], bfr[4];
        #pragma unroll
        for (int mi = 0; mi < 4; ++mi) {
            int r = wm * 64 + mi * 16 + (lane & 15);
            int c = (lane >> 4) ^ ((r >> 1) & 3);
            af[mi] = *(const s16x8*)((const char*)As + r * 64 + c * 16);
        }
        #pragma unroll
        for (int ni = 0; ni < 4; ++ni) {
            int r = wn * 64 + ni * 16 + (lane & 15);
            int c = (lane >> 4) ^ ((r >> 1) & 3);
            bfr[ni] = *(const s16x8*)((const char*)Bs + r * 64 + c * 16);
        }
        #pragma unroll
        for (int mi = 0; mi < 4; ++mi)
            #pragma unroll
            for (int ni = 0; ni < 4; ++ni)
                acc[mi][ni] = __builtin_amdgcn_mfma_f32_16x16x32_bf16(af[mi], bfr[ni], acc[mi][ni], 0, 0, 0);
        __syncthreads();
    }

    // epilogue: C/D layout col=lane&15, row=(lane>>4)*4+reg (HW-verified mapping)
    #pragma unroll
    for (int ni = 0; ni < 4; ++ni) {
        const int col = bn + wn * 64 + ni * 16 + (lane & 15);
        const bool valid = (col < N);
        const float bc = (valid && bias) ? bias[col] : 0.f;
        #pragma unroll
        for (int mi = 0; mi < 4; ++mi) {
            #pragma unroll
            for (int reg = 0; reg < 4; ++reg) {
                const int row = bm + wm * 64 + mi * 16 + (lane >> 4) * 4 + reg;
                float y = 0.f;
                if (valid) {
                    float x = acc[mi][ni][reg] + bc;
                    if (ACT == 1)      y = 0.5f * x * (1.0f + erff(x * 0.7071067811865475f));
                    else if (ACT == 2) y = 1.0f / (1.0f + expf(-x));
                    else if (ACT == 3) { float sg = 1.0f / (1.0f + expf(-tanhf(x))); y = expf(-DECAY_C_F * sg); }
                    else               y = x;
                }
                if (valid || PADZ) {
                    if (OBF) ((__hip_bfloat16*)Cptr)[(size_t)row * ldC + col] = __float2bfloat16(y);
                    else     ((float*)Cptr)[(size_t)row * ldC + col] = y;
                }
            }
        }
    }
}

// ---------------- sequential recurrence v2 ----------------
// 1 block per (b,h); 4 waves; lane = row-channel j; wave owns 16 state columns in VGPRs.
// 1 barrier/step (ping-pong LDS for cross-wave out reduction).
__global__ __launch_bounds__(256) void recurrence2(
    const float* __restrict__ kbuf, const float* iclr, const __hip_bfloat16* __restrict__ dbuf,
    const float* __restrict__ vbuf, const float* __restrict__ rbuf,
    const float* __restrict__ rem_mult, const float* __restrict__ iclr_mix,
    const float* __restrict__ bonus_mult,
    float* outb) {
    const int bh = blockIdx.x;
    const int b = bh >> 4, h = bh & 15;
    const int tid = threadIdx.x, lane = tid & 63, wid = tid >> 6;

    __shared__ float outp[2][4][64];

    float S[16];
    #pragma unroll
    for (int i = 0; i < 16; ++i) S[i] = 0.f;

    const int ch = h * NN + lane;
    const float rem = rem_mult[ch];
    const float mix = iclr_mix[ch];
    const float bon = bonus_mult[ch];

    const size_t base = ((size_t)b * TT) * CC + (size_t)h * NN + lane;

    // prefetch t=0
    float kx = kbuf[base], ax = iclr[base], vx = vbuf[base], rx = rbuf[base];
    float dx = __bfloat162float(dbuf[base]);

    for (int t = 0; t < TT; ++t) {
        // prefetch next step (uniform branch)
        float kN = 0.f, aN = 0.f, vN = 0.f, rN = 0.f, dN = 0.f;
        if (t < TT - 1) {
            const size_t offn = base + (size_t)(t + 1) * CC;
            kN = kbuf[offn]; aN = iclr[offn]; vN = vbuf[offn]; rN = rbuf[offn];
            dN = __bfloat162float(dbuf[offn]);
        }
        // derived scalars (lane = channel j)
        float krm = kx * rem;
        float ss = krm * krm;
        #pragma unroll
        for (int s = 32; s; s >>= 1) ss += __shfl_xor(ss, s);
        float nrm = fmaxf(sqrtf(ss), 1e-12f);
        float kn = krm / nrm;
        float rkx = kx * (1.f + (ax - 1.f) * mix);
        float wq = ax * kn;
        float dot = rx * rkx;
        #pragma unroll
        for (int s = 32; s; s >>= 1) dot += __shfl_xor(dot, s);
        float bonus = dot * 0.2f * vx * bon;

        // gather this wave's column values
        float rkc[16], rc[16];
        #pragma unroll
        for (int cc = 0; cc < 16; ++cc) {
            rkc[cc] = __shfl(rkx, wid * 16 + cc);
            rc[cc]  = __shfl(rx,  wid * 16 + cc);
        }
        // tmp[c] = sum_j w[j]*S[j][c]  (butterfly over 64 lanes, 16 cols in flight)
        float tp[16];
        #pragma unroll
        for (int cc = 0; cc < 16; ++cc) tp[cc] = wq * S[cc];
        #pragma unroll
        for (int s = 1; s < 64; s <<= 1) {
            #pragma unroll
            for (int cc = 0; cc < 16; ++cc) tp[cc] += __shfl_xor(tp[cc], s);
        }
        // state update + out partial
        float po = 0.f;
        #pragma unroll
        for (int cc = 0; cc < 16; ++cc) {
            S[cc] = fmaf(dx, S[cc], fmaf(-kn, tp[cc], vx * rkc[cc]));
            po = fmaf(S[cc], rc[cc], po);
        }
        outp[t & 1][wid][lane] = po;
        __syncthreads();
        if (tid < 64) {
            float o = outp[t & 1][0][lane] + outp[t & 1][1][lane] +
                      outp[t & 1][2][lane] + outp[t & 1][3][lane] + bonus;
            outb[base + (size_t)t * CC] = o;
        }
        kx = kN; ax = aN; vx = vN; rx = rN; dx = dN;
    }
}

// ---------------- LayerNorm * gate (bf16 out) ----------------
__global__ __launch_bounds__(256) void ln_gate_kernel(const float* __restrict__ x,
                                                      const __hip_bfloat16* __restrict__ gate,
                                                      const float* __restrict__ g,
                                                      const float* __restrict__ bv,
                                                      __hip_bfloat16* __restrict__ y) {
    const int row = blockIdx.x;
    const float* xr = x + (size_t)row * CC;
    float v[4];
    float s = 0.f;
    #pragma unroll
    for (int j = 0; j < 4; ++j) { v[j] = xr[threadIdx.x + 256 * j]; s += v[j]; }
    __shared__ float red[4], red2[4];
    #pragma unroll
    for (int o = 32; o; o >>= 1) s += __shfl_xor(s, o);
    if ((threadIdx.x & 63) == 0) red[threadIdx.x >> 6] = s;
    __syncthreads();
    const float mean = (red[0] + red[1] + red[2] + red[3]) * (1.f / CC);
    float vs = 0.f;
    #pragma unroll
    for (int j = 0; j < 4; ++j) { float d = v[j] - mean; vs += d * d; }
    #pragma unroll
    for (int o = 32; o; o >>= 1) vs += __shfl_xor(vs, o);
    if ((threadIdx.x & 63) == 0) red2[threadIdx.x >> 6] = vs;
    __syncthreads();
    const float var = (red2[0] + red2[1] + red2[2] + red2[3]) * (1.f / CC);
    const float rstd = rsqrtf(var + 1e-6f);
    #pragma unroll
    for (int j = 0; j < 4; ++j) {
        const int cc = threadIdx.x + 256 * j;
        float o_ = (v[j] - mean) * rstd * g[cc] + bv[cc];
        float gt = __bfloat162float(gate[(size_t)row * CC + cc]);
        y[(size_t)row * CC + cc] = __float2bfloat16(o_ * gt);
    }
}

// ---------------- launch ----------------
extern "C" void kernel_launch(void* const* d_in, const int* in_sizes, int n_in,
                              void* d_out, int out_size, void* d_ws, size_t ws_size,
                              hipStream_t stream) {
    const float* q        = (const float*)d_in[0];
    const float* mu_r     = (const float*)d_in[4];
    const float* mu_k     = (const float*)d_in[5];
    const float* mu_v     = (const float*)d_in[6];
    const float* mu_g     = (const float*)d_in[7];
    const float* mu_a     = (const float*)d_in[8];
    const float* mu_d     = (const float*)d_in[9];
    const float* dA       = (const float*)d_in[10];
    const float* dB       = (const float*)d_in[11];
    const float* db       = (const float*)d_in[12];
    const float* aA       = (const float*)d_in[13];
    const float* aB       = (const float*)d_in[14];
    const float* ab       = (const float*)d_in[15];
    const float* gA       = (const float*)d_in[16];
    const float* gB       = (const float*)d_in[17];
    const float* rW1      = (const float*)d_in[18];
    const float* rb1      = (const float*)d_in[19];
    const float* rW2      = (const float*)d_in[20];
    const float* rb2      = (const float*)d_in[21];
    const float* kW1      = (const float*)d_in[22];
    const float* kb1      = (const float*)d_in[23];
    const float* kW2      = (const float*)d_in[24];
    const float* kb2      = (const float*)d_in[25];
    const float* vW1      = (const float*)d_in[26];
    const float* vb1      = (const float*)d_in[27];
    const float* vW2      = (const float*)d_in[28];
    const float* vb2      = (const float*)d_in[29];
    const float* oW1      = (const float*)d_in[30];
    const float* ob1      = (const float*)d_in[31];
    const float* oW2      = (const float*)d_in[32];
    const float* ob2      = (const float*)d_in[33];
    const float* rem_mult = (const float*)d_in[34];
    const float* iclr_mix = (const float*)d_in[35];
    const float* bonus_mult = (const float*)d_in[36];
    const float* ln_g     = (const float*)d_in[37];
    const float* ln_b     = (const float*)d_in[38];
    float* out = (float*)d_out;

    // ---- workspace arena ----
    char* p = (char*)d_ws;
    auto alloc = [&](size_t bytes) { char* r = p; p += (bytes + 255) & ~(size_t)255; return r; };
    float* fbr = (float*)alloc(EPAD * 4);
    float* fbk = (float*)alloc(EPAD * 4);
    float* fbv = (float*)alloc(EPAD * 4);
    float* cg2 = (float*)alloc(CC * 4);
    float* ca2 = (float*)alloc(CC * 4);
    float* cd2 = (float*)alloc(CC * 4);
    float* lt  = (float*)alloc(LL * 4);
    __hip_bfloat16* qb   = (__hip_bfloat16*)alloc((size_t)MM * CC * 2);   // also ln_out later
    __hip_bfloat16* rW1T = (__hip_bfloat16*)alloc((size_t)EPAD * CC * 2);
    __hip_bfloat16* kW1T = (__hip_bfloat16*)alloc((size_t)EPAD * CC * 2);
    __hip_bfloat16* vW1T = (__hip_bfloat16*)alloc((size_t)EPAD * CC * 2);
    __hip_bfloat16* oW1T = (__hip_bfloat16*)alloc((size_t)EPAD * CC * 2);
    __hip_bfloat16* rW2T = (__hip_bfloat16*)alloc((size_t)CC * EPAD * 2);
    __hip_bfloat16* kW2T = (__hip_bfloat16*)alloc((size_t)CC * EPAD * 2);
    __hip_bfloat16* vW2T = (__hip_bfloat16*)alloc((size_t)CC * EPAD * 2);
    __hip_bfloat16* oW2T = (__hip_bfloat16*)alloc((size_t)CC * EPAD * 2);
    __hip_bfloat16* gAT  = (__hip_bfloat16*)alloc((size_t)LL * CC * 2);
    __hip_bfloat16* aAT  = (__hip_bfloat16*)alloc((size_t)LL * CC * 2);
    __hip_bfloat16* dAT  = (__hip_bfloat16*)alloc((size_t)LL * CC * 2);
    __hip_bfloat16* gBT  = (__hip_bfloat16*)alloc((size_t)CC * LL * 2);
    __hip_bfloat16* aBT  = (__hip_bfloat16*)alloc((size_t)CC * LL * 2);
    __hip_bfloat16* dBT  = (__hip_bfloat16*)alloc((size_t)CC * LL * 2);
    __hip_bfloat16* Hb   = (__hip_bfloat16*)alloc((size_t)MM * EPAD * 2);
    __hip_bfloat16* tg   = Hb;                       // LoRA intermediates alias H (used before H)
    __hip_bfloat16* ta   = Hb + (size_t)MM * LL;
    __hip_bfloat16* td   = Hb + (size_t)2 * MM * LL;
    float* rbuf = (float*)alloc((size_t)MM * CC * 4);
    float* kbuf = (float*)alloc((size_t)MM * CC * 4);
    float* vbuf = (float*)alloc((size_t)MM * CC * 4);
    float* abuf = (float*)alloc((size_t)MM * CC * 4);               // iclr -> recurrence out
    __hip_bfloat16* dbuf = (__hip_bfloat16*)alloc((size_t)MM * CC * 2);
    __hip_bfloat16* gbuf = (__hip_bfloat16*)alloc((size_t)MM * CC * 2);

    const dim3 blk(256);
    const dim3 tblk(32, 8);

    // casts & transposes
    cast_f32_bf16<<<dim3((MM * CC / 4 + 255) / 256), blk, 0, stream>>>(q, qb, MM * CC / 4);
    transpose_cast<<<dim3(32, 40), tblk, 0, stream>>>(rW1, rW1T, CC, EE, CC, EPAD);
    transpose_cast<<<dim3(32, 40), tblk, 0, stream>>>(kW1, kW1T, CC, EE, CC, EPAD);
    transpose_cast<<<dim3(32, 40), tblk, 0, stream>>>(vW1, vW1T, CC, EE, CC, EPAD);
    transpose_cast<<<dim3(32, 40), tblk, 0, stream>>>(oW1, oW1T, CC, EE, CC, EPAD);
    transpose_cast<<<dim3(40, 32), tblk, 0, stream>>>(rW2, rW2T, EE, CC, EPAD, CC);
    transpose_cast<<<dim3(40, 32), tblk, 0, stream>>>(kW2, kW2T, EE, CC, EPAD, CC);
    transpose_cast<<<dim3(40, 32), tblk, 0, stream>>>(vW2, vW2T, EE, CC, EPAD, CC);
    transpose_cast<<<dim3(40, 32), tblk, 0, stream>>>(oW2, oW2T, EE, CC, EPAD, CC);
    transpose_cast<<<dim3(32, 4), tblk, 0, stream>>>(gA, gAT, CC, LL, CC, LL);
    transpose_cast<<<dim3(32, 4), tblk, 0, stream>>>(aA, aAT, CC, LL, CC, LL);
    transpose_cast<<<dim3(32, 4), tblk, 0, stream>>>(dA, dAT, CC, LL, CC, LL);
    transpose_cast<<<dim3(4, 32), tblk, 0, stream>>>(gB, gBT, LL, CC, LL, CC);
    transpose_cast<<<dim3(4, 32), tblk, 0, stream>>>(aB, aBT, LL, CC, LL, CC);
    transpose_cast<<<dim3(4, 32), tblk, 0, stream>>>(dB, dBT, LL, CC, LL, CC);

    // bias folding
    fold_bias_E<<<dim3((EE + 255) / 256), blk, 0, stream>>>(mu_r, rW1, rb1, fbr, CC, EE);
    fold_bias_E<<<dim3((EE + 255) / 256), blk, 0, stream>>>(mu_k, kW1, kb1, fbk, CC, EE);
    fold_bias_E<<<dim3((EE + 255) / 256), blk, 0, stream>>>(mu_v, vW1, vb1, fbv, CC, EE);
    fold_lora_t<<<dim3(1), dim3(128), 0, stream>>>(mu_g, gA, lt, CC, LL);
    fold_lora_c<<<dim3(4), blk, 0, stream>>>(lt, gB, nullptr, cg2, LL, CC);
    fold_lora_t<<<dim3(1), dim3(128), 0, stream>>>(mu_a, aA, lt, CC, LL);
    fold_lora_c<<<dim3(4), blk, 0, stream>>>(lt, aB, ab, ca2, LL, CC);
    fold_lora_t<<<dim3(1), dim3(128), 0, stream>>>(mu_d, dA, lt, CC, LL);
    fold_lora_c<<<dim3(4), blk, 0, stream>>>(lt, dB, db, cd2, LL, CC);

    const dim3 gLA(1, MM / 128);          // N=128
    const dim3 gC(CC / 128, MM / 128);    // N=1024
    const dim3 gE(EPAD / 128, MM / 128);  // N=1228 padded to 1280

    // LoRA A-stage: t = q @ A   (bf16 out)
    gemm_mfma<0,1,0><<<gLA, blk, 0, stream>>>(qb, gAT, nullptr, tg, MM, LL, CC, CC, CC, LL);
    gemm_mfma<0,1,0><<<gLA, blk, 0, stream>>>(qb, aAT, nullptr, ta, MM, LL, CC, CC, CC, LL);
    gemm_mfma<0,1,0><<<gLA, blk, 0, stream>>>(qb, dAT, nullptr, td, MM, LL, CC, CC, CC, LL);
    // LoRA B-stage
    gemm_mfma<2,1,0><<<gC, blk, 0, stream>>>(tg, gBT, cg2, gbuf, MM, CC, LL, LL, LL, CC);
    gemm_mfma<2,0,0><<<gC, blk, 0, stream>>>(ta, aBT, ca2, abuf, MM, CC, LL, LL, LL, CC);
    gemm_mfma<3,1,0><<<gC, blk, 0, stream>>>(td, dBT, cd2, dbuf, MM, CC, LL, LL, LL, CC);

    // MLPs r/k/v (note: Hb overwrites tg/ta/td — only after LoRA B-stage)
    gemm_mfma<1,1,1><<<gE, blk, 0, stream>>>(qb, rW1T, fbr, Hb, MM, EE, CC, CC, CC, EPAD);
    gemm_mfma<0,0,0><<<gC, blk, 0, stream>>>(Hb, rW2T, rb2, rbuf, MM, CC, EPAD, EPAD, EPAD, CC);
    gemm_mfma<1,1,1><<<gE, blk, 0, stream>>>(qb, kW1T, fbk, Hb, MM, EE, CC, CC, CC, EPAD);
    gemm_mfma<0,0,0><<<gC, blk, 0, stream>>>(Hb, kW2T, kb2, kbuf, MM, CC, EPAD, EPAD, EPAD, CC);
    gemm_mfma<1,1,1><<<gE, blk, 0, stream>>>(qb, vW1T, fbv, Hb, MM, EE, CC, CC, CC, EPAD);
    gemm_mfma<0,0,0><<<gC, blk, 0, stream>>>(Hb, vW2T, vb2, vbuf, MM, CC, EPAD, EPAD, EPAD, CC);

    // recurrence (writes into abuf, aliasing iclr element-wise)
    recurrence2<<<dim3(BB * HH), blk, 0, stream>>>(kbuf, abuf, dbuf, vbuf, rbuf,
                                                   rem_mult, iclr_mix, bonus_mult, abuf);

    // LN * gate -> bf16 (reuse qb region; q no longer needed)
    ln_gate_kernel<<<dim3(MM), blk, 0, stream>>>(abuf, gbuf, ln_g, ln_b, qb);

    // output MLP
    gemm_mfma<1,1,1><<<gE, blk, 0, stream>>>(qb, oW1T, ob1, Hb, MM, EE, CC, CC, CC, EPAD);
    gemm_mfma<0,0,0><<<gC, blk, 0, stream>>>(Hb, oW2T, ob2, out, MM, CC, EPAD, EPAD, EPAD, CC);
}

// Round 3
// 3330.533 us; speedup vs baseline: 3.0131x; 1.7778x over previous
//
#include <hip/hip_runtime.h>
#include <hip/hip_bf16.h>
#include <math.h>

// LinearAttentionLayerOptimized: B=4, T=2048, C=1024, H=16, N=64, L=128, E=1228
// Round 2: chunked WY-transform recurrence (fp32, LDS-resident, Tc=32) + bf16 MFMA GEMMs.

#define BB 4
#define TT 2048
#define CC 1024
#define HH 16
#define NN 64
#define LL 128
#define EE 1228
#define EPAD 1280
#define MM (BB*TT)          // 8192 rows
#define TCH 32
#define DECAY_C_F 0.7408182206817179f

typedef __attribute__((ext_vector_type(8))) short s16x8;
typedef __attribute__((ext_vector_type(4))) float f32x4;

#define GLOAD_LDS16(gp, lp) \
    __builtin_amdgcn_global_load_lds((const __attribute__((address_space(1))) void*)(gp), \
                                     (__attribute__((address_space(3))) void*)(lp), 16, 0, 0)

// ---------------- bias folding ----------------
// outb[e] = b1[e] + sum_c mu[c]*W1[c*E+e]; grid = ceil(E/64), 256 threads (4-way k-split)
__global__ void fold_bias_E2(const float* __restrict__ mu, const float* __restrict__ W1,
                             const float* __restrict__ b1, float* __restrict__ outb,
                             int C, int E) {
    const int l = threadIdx.x & 63;
    const int e = blockIdx.x * 64 + l;
    const int kg = threadIdx.x >> 6;
    float s = 0.f;
    if (e < E) for (int c = kg; c < C; c += 4) s += mu[c] * W1[(size_t)c * E + e];
    __shared__ float red[4][64];
    red[kg][l] = s;
    __syncthreads();
    if (kg == 0 && e < E) outb[e] = b1[e] + red[0][l] + red[1][l] + red[2][l] + red[3][l];
}

__global__ void fold_lora_t(const float* __restrict__ mu, const float* __restrict__ Amat,
                            float* __restrict__ ltmp, int C, int L) {
    int l = blockIdx.x * blockDim.x + threadIdx.x;
    if (l >= L) return;
    float s = 0.f;
    for (int c = 0; c < C; ++c) s += mu[c] * Amat[(size_t)c * L + l];
    ltmp[l] = s;
}

__global__ void fold_lora_c(const float* __restrict__ ltmp, const float* __restrict__ Bm,
                            const float* __restrict__ bias, float* __restrict__ outc,
                            int L, int C) {
    int c = blockIdx.x * blockDim.x + threadIdx.x;
    if (c >= C) return;
    float s = bias ? bias[c] : 0.f;
    for (int l = 0; l < L; ++l) s += ltmp[l] * Bm[(size_t)l * C + c];
    outc[c] = s;
}

// ---------------- cast / transpose-cast ----------------
__global__ void cast_f32_bf16(const float* __restrict__ in, __hip_bfloat16* __restrict__ out, int n4) {
    int i = blockIdx.x * blockDim.x + threadIdx.x;
    if (i >= n4) return;
    float4 v = ((const float4*)in)[i];
    __hip_bfloat16 o[4] = {__float2bfloat16(v.x), __float2bfloat16(v.y),
                           __float2bfloat16(v.z), __float2bfloat16(v.w)};
    *(ulong1*)&out[i * 4] = *(ulong1*)o;
}

__global__ void transpose_cast(const float* __restrict__ in, __hip_bfloat16* __restrict__ outT,
                               int Rin, int Cin, int Rpad, int Cpad) {
    __shared__ float t[32][33];
    const int r0 = blockIdx.x * 32, c0 = blockIdx.y * 32;
    const int tx = threadIdx.x, ty = threadIdx.y;   // 32 x 8
    #pragma unroll
    for (int j = 0; j < 4; ++j) {
        int r = r0 + ty + j * 8, c = c0 + tx;
        t[ty + j * 8][tx] = (r < Rin && c < Cin) ? in[(size_t)r * Cin + c] : 0.f;
    }
    __syncthreads();
    #pragma unroll
    for (int j = 0; j < 4; ++j) {
        int c = c0 + ty + j * 8, r = r0 + tx;
        if (c < Cpad && r < Rpad) outT[(size_t)c * Rpad + r] = __float2bfloat16(t[tx][ty + j * 8]);
    }
}

// ---------------- bf16 MFMA GEMM (unchanged from round 1) ----------------
template<int ACT, int OBF, int PADZ>
__global__ __launch_bounds__(256) void gemm_mfma(const __hip_bfloat16* __restrict__ A,
                                                 const __hip_bfloat16* __restrict__ Bt,
                                                 const float* __restrict__ bias,
                                                 void* __restrict__ Cptr,
                                                 int M, int N, int K,
                                                 int ldA, int ldB, int ldC) {
    __shared__ __hip_bfloat16 As[128 * 32];
    __shared__ __hip_bfloat16 Bs[128 * 32];
    const int tid = threadIdx.x;
    const int wid = tid >> 6, lane = tid & 63;
    const int wm = wid >> 1, wn = wid & 1;
    const int bm = blockIdx.y * 128, bn = blockIdx.x * 128;

    const __hip_bfloat16* srcA[2];
    const __hip_bfloat16* srcB[2];
    #pragma unroll
    for (int i = 0; i < 2; ++i) {
        int off = (wid * 2 + i) * 1024 + lane * 16;
        int r = off >> 6;
        int c = (off >> 4) & 3;
        int cs = c ^ ((r >> 1) & 3);
        srcA[i] = A  + (size_t)(bm + r) * ldA + cs * 8;
        srcB[i] = Bt + (size_t)(bn + r) * ldB + cs * 8;
    }

    f32x4 acc[4][4];
    #pragma unroll
    for (int i = 0; i < 4; ++i)
        #pragma unroll
        for (int j = 0; j < 4; ++j) acc[i][j] = (f32x4){0.f, 0.f, 0.f, 0.f};

    for (int k0 = 0; k0 < K; k0 += 32) {
        #pragma unroll
        for (int i = 0; i < 2; ++i) {
            GLOAD_LDS16(srcA[i] + k0, (char*)As + (wid * 2 + i) * 1024);
            GLOAD_LDS16(srcB[i] + k0, (char*)Bs + (wid * 2 + i) * 1024);
        }
        __syncthreads();
        s16x8 af[4], bfr[4];
        #pragma unroll
        for (int mi = 0; mi < 4; ++mi) {
            int r = wm * 64 + mi * 16 + (lane & 15);
            int c = (lane >> 4) ^ ((r >> 1) & 3);
            af[mi] = *(const s16x8*)((const char*)As + r * 64 + c * 16);
        }
        #pragma unroll
        for (int ni = 0; ni < 4; ++ni) {
            int r = wn * 64 + ni * 16 + (lane & 15);
            int c = (lane >> 4) ^ ((r >> 1) & 3);
            bfr[ni] = *(const s16x8*)((const char*)Bs + r * 64 + c * 16);
        }
        #pragma unroll
        for (int mi = 0; mi < 4; ++mi)
            #pragma unroll
            for (int ni = 0; ni < 4; ++ni)
                acc[mi][ni] = __builtin_amdgcn_mfma_f32_16x16x32_bf16(af[mi], bfr[ni], acc[mi][ni], 0, 0, 0);
        __syncthreads();
    }

    #pragma unroll
    for (int ni = 0; ni < 4; ++ni) {
        const int col = bn + wn * 64 + ni * 16 + (lane & 15);
        const bool valid = (col < N);
        const float bc = (valid && bias) ? bias[col] : 0.f;
        #pragma unroll
        for (int mi = 0; mi < 4; ++mi) {
            #pragma unroll
            for (int reg = 0; reg < 4; ++reg) {
                const int row = bm + wm * 64 + mi * 16 + (lane >> 4) * 4 + reg;
                float y = 0.f;
                if (valid) {
                    float x = acc[mi][ni][reg] + bc;
                    if (ACT == 1)      y = 0.5f * x * (1.0f + erff(x * 0.7071067811865475f));
                    else if (ACT == 2) y = 1.0f / (1.0f + expf(-x));
                    else if (ACT == 3) { float sg = 1.0f / (1.0f + expf(-tanhf(x))); y = expf(-DECAY_C_F * sg); }
                    else               y = x;
                }
                if (valid || PADZ) {
                    if (OBF) ((__hip_bfloat16*)Cptr)[(size_t)row * ldC + col] = __float2bfloat16(y);
                    else     ((float*)Cptr)[(size_t)row * ldC + col] = y;
                }
            }
        }
    }
}

// ---------------- chunked recurrence ----------------
// Per chunk (Tc=32), per (b,h):  S_t = (diag(d)-kn w^T)S_{t-1} + v rk^T ; out = S r
// Transform T = diag(1/dc)S: T_t = T_{t-1} - kap_t (wt_t^T T_{t-1}) + nu_t rk_t^T
// G rows g_t solve (I+A_sl)G = WT~.T0 + B_sl.RK ;  A[t][s]=wt_t.kap_s, B[t][s]=wt_t.nu_s
// out_t = dc_t*(T0 r_t + sum_{s<=t} nu_s(rk_s.r_t) - sum_{s<=t} kap_s(g_s.r_t)) + bonus
// T0 <- dc_Tc * (T0 - Kap^T G + Nu^T RK)
// LDS pool views (floats, strides 68 / 36):
#define P_T0(i,j)   pool[0     + (i)*68 + (j)]
#define P_WT(i,j)   pool[4352  + (i)*68 + (j)]
#define P_KP(i,j)   pool[6528  + (i)*68 + (j)]
#define P_P2t(i,j)  pool[6528  + (i)*36 + (j)]   // aliases KP (dead after phase2)
#define P_NU(i,j)   pool[8704  + (i)*68 + (j)]
#define P_GRt(i,j)  pool[8704  + (i)*36 + (j)]   // aliases NU (dead after phase2)
#define P_RKM(i,j)  pool[10880 + (i)*68 + (j)]
#define P_RRM(i,j)  pool[13056 + (i)*68 + (j)]
#define P_GM(i,j)   pool[15232 + (i)*68 + (j)]
#define P_GMT(i,j)  pool[17408 + (i)*36 + (j)]
#define P_KPT(i,j)  pool[19712 + (i)*36 + (j)]
#define P_NUT(i,j)  pool[22016 + (i)*36 + (j)]
#define P_RKMT(i,j) pool[24320 + (i)*36 + (j)]
#define P_DCT(i,j)  pool[26624 + (i)*36 + (j)]
#define P_AT(i,j)   pool[28928 + (i)*36 + (j)]
#define P_BM(i,j)   pool[30080 + (i)*36 + (j)]
#define P_SEG(i,j)  pool[31232 + (i)*64 + (j)]
#define LD4(expr)   (*(const float4*)&(expr))

__global__ __launch_bounds__(512) void recurrence_chunked(
    const float* __restrict__ kbuf, const float* iclr, const float* __restrict__ dbuf,
    const float* __restrict__ vbuf, const float* __restrict__ rbuf,
    const float* __restrict__ rem_mult, const float* __restrict__ iclr_mix,
    const float* __restrict__ bonus_mult, float* outb) {
    __shared__ float pool[31488];   // 123 KB
    const int bh = blockIdx.x, b = bh >> 4, h = bh & 15;
    const int tid = threadIdx.x, lane = tid & 63, wid = tid >> 6;
    const size_t gbase = ((size_t)b * TT) * CC + (size_t)h * NN;

    for (int i = tid; i < 4352; i += 512) pool[i] = 0.f;   // T0 = 0
    const int c0 = tid & 63;
    const float remc = rem_mult[h * NN + c0];
    const float mixc = iclr_mix[h * NN + c0];
    __syncthreads();

    for (int chk = 0; chk < TT / TCH; ++chk) {
        const int tg0 = chk * TCH;
        // ---- load & elementwise ----
        #pragma unroll
        for (int i = 0; i < 4; ++i) {
            int idx = tid + 512 * i;
            int t = idx >> 6, c = idx & 63;
            size_t off = gbase + (size_t)(tg0 + t) * CC + c;
            float kx = kbuf[off], ax = iclr[off];
            float rk = kx * (1.f + (ax - 1.f) * mixc);
            P_WT(t, c) = ax;                 // a (-> w -> w~)
            P_KP(t, c) = kx * remc;          // krm (-> kn -> kap)
            P_RKM(t, c) = rk; P_RKMT(c, t) = rk;
            P_NU(t, c) = vbuf[off];          // v (-> nu)
            P_RRM(t, c) = rbuf[off];
            P_DCT(c, t) = dbuf[off];         // raw d (-> dc)
        }
        __syncthreads();
        // ---- row norms: wave w -> rows {w, w+8, w+16, w+24} ----
        #pragma unroll
        for (int rr = 0; rr < 4; ++rr) {
            int t = wid + rr * 8;
            float v = P_KP(t, lane);
            float ss = v * v;
            #pragma unroll
            for (int s = 32; s; s >>= 1) ss += __shfl_xor(ss, s);
            float kn = v / fmaxf(sqrtf(ss), 1e-12f);
            P_KP(t, lane) = kn;
            P_WT(t, lane) = P_WT(t, lane) * kn;   // w = a*kn
        }
        __syncthreads();
        // ---- segmented cumprod + scaled quantities (256 threads: c, seg) ----
        float lc[8];
        int ccs = tid & 63, seg = tid >> 6, t0s = seg * 8;
        if (tid < 256) {
            float p = 1.f;
            #pragma unroll
            for (int j = 0; j < 8; ++j) { p *= P_DCT(ccs, t0s + j); lc[j] = p; }
            P_SEG(seg, ccs) = p;
        }
        __syncthreads();
        if (tid < 256) {
            float m = 1.f;
            for (int s = 0; s < seg; ++s) m *= P_SEG(s, ccs);
            float dcprev = m;
            #pragma unroll
            for (int j = 0; j < 8; ++j) {
                int t = t0s + j;
                float dcur = m * lc[j];
                P_WT(t, ccs) *= dcprev;            // w~ = w * dc_{t-1}
                float inv = 1.f / dcur;
                float kap = P_KP(t, ccs) * inv; P_KP(t, ccs) = kap; P_KPT(ccs, t) = kap;
                float nu  = P_NU(t, ccs) * inv; P_NU(t, ccs) = nu;  P_NUT(ccs, t) = nu;
                P_DCT(ccs, t) = dcur;
                dcprev = dcur;
            }
        }
        __syncthreads();
        // ---- phase2: AT, BM (strict-lower), RHS1 -> GM  (64 tiles of 8x8) ----
        for (int tile = wid; tile < 64; tile += 8) {
            if (tile < 16) {            // AT[s][t] = wt_t . kap_s  (s<t)
                int s = (tile >> 2) * 8 + (lane >> 3), t = (tile & 3) * 8 + (lane & 7);
                float acc = 0.f;
                #pragma unroll
                for (int kc = 0; kc < 16; ++kc) {
                    float4 a = LD4(P_KP(s, kc * 4));
                    float4 bb = LD4(P_WT(t, kc * 4));
                    acc += a.x * bb.x + a.y * bb.y + a.z * bb.z + a.w * bb.w;
                }
                P_AT(s, t) = (s < t) ? acc : 0.f;
            } else if (tile < 32) {     // BM[t][s] = wt_t . nu_s  (s<t)
                int t = ((tile - 16) >> 2) * 8 + (lane >> 3), s = ((tile - 16) & 3) * 8 + (lane & 7);
                float acc = 0.f;
                #pragma unroll
                for (int kc = 0; kc < 16; ++kc) {
                    float4 a = LD4(P_WT(t, kc * 4));
                    float4 bb = LD4(P_NU(s, kc * 4));
                    acc += a.x * bb.x + a.y * bb.y + a.z * bb.z + a.w * bb.w;
                }
                P_BM(t, s) = (s < t) ? acc : 0.f;
            } else {                    // GM[t][q] = sum_j wt[t][j] * T0[j][q]
                int tt = tile - 32;
                int t = (tt >> 3) * 8 + (lane >> 3), q = (tt & 7) * 8 + (lane & 7);
                float acc = 0.f;
                #pragma unroll
                for (int j4 = 0; j4 < 16; ++j4) {
                    float4 a = LD4(P_WT(t, j4 * 4));
                    acc += a.x * P_T0(j4 * 4 + 0, q) + a.y * P_T0(j4 * 4 + 1, q)
                         + a.z * P_T0(j4 * 4 + 2, q) + a.w * P_T0(j4 * 4 + 3, q);
                }
                P_GM(t, q) = acc;
            }
        }
        __syncthreads();
        // ---- phase3: GM[t][q] += sum_s BM[t][s] * RKM[s][q]  (32 tiles) ----
        for (int tile = wid; tile < 32; tile += 8) {
            int t = (tile >> 3) * 8 + (lane >> 3), q = (tile & 7) * 8 + (lane & 7);
            float acc = 0.f;
            #pragma unroll
            for (int s4 = 0; s4 < 8; ++s4) {
                float4 a = LD4(P_BM(t, s4 * 4));
                acc += a.x * P_RKM(s4 * 4 + 0, q) + a.y * P_RKM(s4 * 4 + 1, q)
                     + a.z * P_RKM(s4 * 4 + 2, q) + a.w * P_RKM(s4 * 4 + 3, q);
            }
            P_GM(t, q) += acc;
        }
        __syncthreads();
        // ---- phase4: wave0 forward substitution || waves1-7: P2t ----
        if (wid == 0) {
            float g[32];
            #pragma unroll
            for (int t = 0; t < 32; ++t) g[t] = P_GM(t, lane);
            #pragma unroll
            for (int s = 0; s < 31; ++s) {
                #pragma unroll
                for (int t = s + 1; t < 32; ++t) g[t] -= P_AT(s, t) * g[s];
            }
            #pragma unroll
            for (int t = 0; t < 32; ++t) { P_GM(t, lane) = g[t]; P_GMT(lane, t) = g[t]; }
        } else {
            for (int tile = wid - 1; tile < 16; tile += 7) {   // P2t[t][s] = rk_s . r_t (s<=t)
                int t = (tile >> 2) * 8 + (lane >> 3), s = (tile & 3) * 8 + (lane & 7);
                float acc = 0.f;
                #pragma unroll
                for (int kc = 0; kc < 16; ++kc) {
                    float4 a = LD4(P_RRM(t, kc * 4));
                    float4 bb = LD4(P_RKM(s, kc * 4));
                    acc += a.x * bb.x + a.y * bb.y + a.z * bb.z + a.w * bb.w;
                }
                P_P2t(t, s) = (s <= t) ? acc : 0.f;
            }
        }
        __syncthreads();
        // ---- phase5: GRt[t][s] = g_s . r_t (s<=t)  (16 tiles) ----
        for (int tile = wid; tile < 16; tile += 8) {
            int t = (tile >> 2) * 8 + (lane >> 3), s = (tile & 3) * 8 + (lane & 7);
            float acc = 0.f;
            #pragma unroll
            for (int kc = 0; kc < 16; ++kc) {
                float4 a = LD4(P_RRM(t, kc * 4));
                float4 bb = LD4(P_GM(s, kc * 4));
                acc += a.x * bb.x + a.y * bb.y + a.z * bb.z + a.w * bb.w;
            }
            P_GRt(t, s) = (s <= t) ? acc : 0.f;
        }
        __syncthreads();
        // ---- phase6a: out  (32 tiles of 8x8 over [i][t]) ----
        for (int tile = wid; tile < 32; tile += 8) {
            int i = (tile >> 2) * 8 + (lane >> 3), t = (tile & 3) * 8 + (lane & 7);
            float a1 = 0.f, a2 = 0.f, a3 = 0.f;
            #pragma unroll
            for (int j4 = 0; j4 < 16; ++j4) {
                float4 a = LD4(P_T0(i, j4 * 4));
                float4 bb = LD4(P_RRM(t, j4 * 4));
                a1 += a.x * bb.x + a.y * bb.y + a.z * bb.z + a.w * bb.w;
            }
            #pragma unroll
            for (int s4 = 0; s4 < 8; ++s4) {
                float4 a = LD4(P_NUT(i, s4 * 4));
                float4 bb = LD4(P_P2t(t, s4 * 4));
                a2 += a.x * bb.x + a.y * bb.y + a.z * bb.z + a.w * bb.w;
                float4 c = LD4(P_KPT(i, s4 * 4));
                float4 d = LD4(P_GRt(t, s4 * 4));
                a3 += c.x * d.x + c.y * d.y + c.z * d.z + c.w * d.w;
            }
            float diag = 0.2f * bonus_mult[h * NN + i] * P_NUT(i, t) * P_P2t(t, t);
            outb[gbase + (size_t)(tg0 + t) * CC + i] = P_DCT(i, t) * (a1 + a2 + diag - a3);
        }
        __syncthreads();
        // ---- phase6b: T0 <- dc_end * (T0 - Kap^T G + Nu^T RK)  (64 tiles) ----
        for (int tile = wid; tile < 64; tile += 8) {
            int p = (tile >> 3) * 8 + (lane >> 3), q = (tile & 7) * 8 + (lane & 7);
            float a1 = 0.f, a2 = 0.f;
            #pragma unroll
            for (int s4 = 0; s4 < 8; ++s4) {
                float4 a = LD4(P_KPT(p, s4 * 4));
                float4 bb = LD4(P_GMT(q, s4 * 4));
                a1 += a.x * bb.x + a.y * bb.y + a.z * bb.z + a.w * bb.w;
                float4 c = LD4(P_NUT(p, s4 * 4));
                float4 d = LD4(P_RKMT(q, s4 * 4));
                a2 += c.x * d.x + c.y * d.y + c.z * d.z + c.w * d.w;
            }
            P_T0(p, q) = P_DCT(p, 31) * (P_T0(p, q) - a1 + a2);
        }
        __syncthreads();
    }
}

// ---------------- LayerNorm * gate (bf16 out) ----------------
__global__ __launch_bounds__(256) void ln_gate_kernel(const float* __restrict__ x,
                                                      const __hip_bfloat16* __restrict__ gate,
                                                      const float* __restrict__ g,
                                                      const float* __restrict__ bv,
                                                      __hip_bfloat16* __restrict__ y) {
    const int row = blockIdx.x;
    const float* xr = x + (size_t)row * CC;
    float v[4];
    float s = 0.f;
    #pragma unroll
    for (int j = 0; j < 4; ++j) { v[j] = xr[threadIdx.x + 256 * j]; s += v[j]; }
    __shared__ float red[4], red2[4];
    #pragma unroll
    for (int o = 32; o; o >>= 1) s += __shfl_xor(s, o);
    if ((threadIdx.x & 63) == 0) red[threadIdx.x >> 6] = s;
    __syncthreads();
    const float mean = (red[0] + red[1] + red[2] + red[3]) * (1.f / CC);
    float vs = 0.f;
    #pragma unroll
    for (int j = 0; j < 4; ++j) { float d = v[j] - mean; vs += d * d; }
    #pragma unroll
    for (int o = 32; o; o >>= 1) vs += __shfl_xor(vs, o);
    if ((threadIdx.x & 63) == 0) red2[threadIdx.x >> 6] = vs;
    __syncthreads();
    const float var = (red2[0] + red2[1] + red2[2] + red2[3]) * (1.f / CC);
    const float rstd = rsqrtf(var + 1e-6f);
    #pragma unroll
    for (int j = 0; j < 4; ++j) {
        const int cc = threadIdx.x + 256 * j;
        float o_ = (v[j] - mean) * rstd * g[cc] + bv[cc];
        float gt = __bfloat162float(gate[(size_t)row * CC + cc]);
        y[(size_t)row * CC + cc] = __float2bfloat16(o_ * gt);
    }
}

// ---------------- launch ----------------
extern "C" void kernel_launch(void* const* d_in, const int* in_sizes, int n_in,
                              void* d_out, int out_size, void* d_ws, size_t ws_size,
                              hipStream_t stream) {
    const float* q        = (const float*)d_in[0];
    const float* mu_r     = (const float*)d_in[4];
    const float* mu_k     = (const float*)d_in[5];
    const float* mu_v     = (const float*)d_in[6];
    const float* mu_g     = (const float*)d_in[7];
    const float* mu_a     = (const float*)d_in[8];
    const float* mu_d     = (const float*)d_in[9];
    const float* dA       = (const float*)d_in[10];
    const float* dB       = (const float*)d_in[11];
    const float* db       = (const float*)d_in[12];
    const float* aA       = (const float*)d_in[13];
    const float* aB       = (const float*)d_in[14];
    const float* ab       = (const float*)d_in[15];
    const float* gA       = (const float*)d_in[16];
    const float* gB       = (const float*)d_in[17];
    const float* rW1      = (const float*)d_in[18];
    const float* rb1      = (const float*)d_in[19];
    const float* rW2      = (const float*)d_in[20];
    const float* rb2      = (const float*)d_in[21];
    const float* kW1      = (const float*)d_in[22];
    const float* kb1      = (const float*)d_in[23];
    const float* kW2      = (const float*)d_in[24];
    const float* kb2      = (const float*)d_in[25];
    const float* vW1      = (const float*)d_in[26];
    const float* vb1      = (const float*)d_in[27];
    const float* vW2      = (const float*)d_in[28];
    const float* vb2      = (const float*)d_in[29];
    const float* oW1      = (const float*)d_in[30];
    const float* ob1      = (const float*)d_in[31];
    const float* oW2      = (const float*)d_in[32];
    const float* ob2      = (const float*)d_in[33];
    const float* rem_mult = (const float*)d_in[34];
    const float* iclr_mix = (const float*)d_in[35];
    const float* bonus_mult = (const float*)d_in[36];
    const float* ln_g     = (const float*)d_in[37];
    const float* ln_b     = (const float*)d_in[38];
    float* out = (float*)d_out;

    // ---- workspace arena ----
    char* p = (char*)d_ws;
    auto alloc = [&](size_t bytes) { char* r = p; p += (bytes + 255) & ~(size_t)255; return r; };
    float* fbr = (float*)alloc(EPAD * 4);
    float* fbk = (float*)alloc(EPAD * 4);
    float* fbv = (float*)alloc(EPAD * 4);
    float* cg2 = (float*)alloc(CC * 4);
    float* ca2 = (float*)alloc(CC * 4);
    float* cd2 = (float*)alloc(CC * 4);
    float* lt  = (float*)alloc(LL * 4);
    __hip_bfloat16* qb   = (__hip_bfloat16*)alloc((size_t)MM * CC * 2);   // also ln_out later
    __hip_bfloat16* rW1T = (__hip_bfloat16*)alloc((size_t)EPAD * CC * 2);
    __hip_bfloat16* kW1T = (__hip_bfloat16*)alloc((size_t)EPAD * CC * 2);
    __hip_bfloat16* vW1T = (__hip_bfloat16*)alloc((size_t)EPAD * CC * 2);
    __hip_bfloat16* oW1T = (__hip_bfloat16*)alloc((size_t)EPAD * CC * 2);
    __hip_bfloat16* rW2T = (__hip_bfloat16*)alloc((size_t)CC * EPAD * 2);
    __hip_bfloat16* kW2T = (__hip_bfloat16*)alloc((size_t)CC * EPAD * 2);
    __hip_bfloat16* vW2T = (__hip_bfloat16*)alloc((size_t)CC * EPAD * 2);
    __hip_bfloat16* oW2T = (__hip_bfloat16*)alloc((size_t)CC * EPAD * 2);
    __hip_bfloat16* gAT  = (__hip_bfloat16*)alloc((size_t)LL * CC * 2);
    __hip_bfloat16* aAT  = (__hip_bfloat16*)alloc((size_t)LL * CC * 2);
    __hip_bfloat16* dAT  = (__hip_bfloat16*)alloc((size_t)LL * CC * 2);
    __hip_bfloat16* gBT  = (__hip_bfloat16*)alloc((size_t)CC * LL * 2);
    __hip_bfloat16* aBT  = (__hip_bfloat16*)alloc((size_t)CC * LL * 2);
    __hip_bfloat16* dBT  = (__hip_bfloat16*)alloc((size_t)CC * LL * 2);
    __hip_bfloat16* Hb   = (__hip_bfloat16*)alloc((size_t)MM * EPAD * 2);
    __hip_bfloat16* tg   = Hb;                       // LoRA intermediates alias Hb
    __hip_bfloat16* ta   = Hb + (size_t)MM * LL;
    __hip_bfloat16* td   = Hb + (size_t)2 * MM * LL;
    float* rbuf = (float*)alloc((size_t)MM * CC * 4);
    float* kbuf = (float*)alloc((size_t)MM * CC * 4);
    float* vbuf = (float*)alloc((size_t)MM * CC * 4);
    float* abuf = (float*)alloc((size_t)MM * CC * 4);   // iclr -> recurrence out
    float* dbuf = (float*)alloc((size_t)MM * CC * 4);   // decay (f32 now)
    __hip_bfloat16* gbuf = (__hip_bfloat16*)alloc((size_t)MM * CC * 2);

    const dim3 blk(256);
    const dim3 tblk(32, 8);

    // casts & transposes
    cast_f32_bf16<<<dim3((MM * CC / 4 + 255) / 256), blk, 0, stream>>>(q, qb, MM * CC / 4);
    transpose_cast<<<dim3(32, 40), tblk, 0, stream>>>(rW1, rW1T, CC, EE, CC, EPAD);
    transpose_cast<<<dim3(32, 40), tblk, 0, stream>>>(kW1, kW1T, CC, EE, CC, EPAD);
    transpose_cast<<<dim3(32, 40), tblk, 0, stream>>>(vW1, vW1T, CC, EE, CC, EPAD);
    transpose_cast<<<dim3(32, 40), tblk, 0, stream>>>(oW1, oW1T, CC, EE, CC, EPAD);
    transpose_cast<<<dim3(40, 32), tblk, 0, stream>>>(rW2, rW2T, EE, CC, EPAD, CC);
    transpose_cast<<<dim3(40, 32), tblk, 0, stream>>>(kW2, kW2T, EE, CC, EPAD, CC);
    transpose_cast<<<dim3(40, 32), tblk, 0, stream>>>(vW2, vW2T, EE, CC, EPAD, CC);
    transpose_cast<<<dim3(40, 32), tblk, 0, stream>>>(oW2, oW2T, EE, CC, EPAD, CC);
    transpose_cast<<<dim3(32, 4), tblk, 0, stream>>>(gA, gAT, CC, LL, CC, LL);
    transpose_cast<<<dim3(32, 4), tblk, 0, stream>>>(aA, aAT, CC, LL, CC, LL);
    transpose_cast<<<dim3(32, 4), tblk, 0, stream>>>(dA, dAT, CC, LL, CC, LL);
    transpose_cast<<<dim3(4, 32), tblk, 0, stream>>>(gB, gBT, LL, CC, LL, CC);
    transpose_cast<<<dim3(4, 32), tblk, 0, stream>>>(aB, aBT, LL, CC, LL, CC);
    transpose_cast<<<dim3(4, 32), tblk, 0, stream>>>(dB, dBT, LL, CC, LL, CC);

    // bias folding
    fold_bias_E2<<<dim3((EE + 63) / 64), blk, 0, stream>>>(mu_r, rW1, rb1, fbr, CC, EE);
    fold_bias_E2<<<dim3((EE + 63) / 64), blk, 0, stream>>>(mu_k, kW1, kb1, fbk, CC, EE);
    fold_bias_E2<<<dim3((EE + 63) / 64), blk, 0, stream>>>(mu_v, vW1, vb1, fbv, CC, EE);
    fold_lora_t<<<dim3(1), dim3(128), 0, stream>>>(mu_g, gA, lt, CC, LL);
    fold_lora_c<<<dim3(4), blk, 0, stream>>>(lt, gB, nullptr, cg2, LL, CC);
    fold_lora_t<<<dim3(1), dim3(128), 0, stream>>>(mu_a, aA, lt, CC, LL);
    fold_lora_c<<<dim3(4), blk, 0, stream>>>(lt, aB, ab, ca2, LL, CC);
    fold_lora_t<<<dim3(1), dim3(128), 0, stream>>>(mu_d, dA, lt, CC, LL);
    fold_lora_c<<<dim3(4), blk, 0, stream>>>(lt, dB, db, cd2, LL, CC);

    const dim3 gLA(1, MM / 128);          // N=128
    const dim3 gC(CC / 128, MM / 128);    // N=1024
    const dim3 gE(EPAD / 128, MM / 128);  // N=1228 -> 1280

    // LoRA A-stage
    gemm_mfma<0,1,0><<<gLA, blk, 0, stream>>>(qb, gAT, nullptr, tg, MM, LL, CC, CC, CC, LL);
    gemm_mfma<0,1,0><<<gLA, blk, 0, stream>>>(qb, aAT, nullptr, ta, MM, LL, CC, CC, CC, LL);
    gemm_mfma<0,1,0><<<gLA, blk, 0, stream>>>(qb, dAT, nullptr, td, MM, LL, CC, CC, CC, LL);
    // LoRA B-stage
    gemm_mfma<2,1,0><<<gC, blk, 0, stream>>>(tg, gBT, cg2, gbuf, MM, CC, LL, LL, LL, CC);
    gemm_mfma<2,0,0><<<gC, blk, 0, stream>>>(ta, aBT, ca2, abuf, MM, CC, LL, LL, LL, CC);
    gemm_mfma<3,0,0><<<gC, blk, 0, stream>>>(td, dBT, cd2, dbuf, MM, CC, LL, LL, LL, CC);

    // MLPs r/k/v
    gemm_mfma<1,1,1><<<gE, blk, 0, stream>>>(qb, rW1T, fbr, Hb, MM, EE, CC, CC, CC, EPAD);
    gemm_mfma<0,0,0><<<gC, blk, 0, stream>>>(Hb, rW2T, rb2, rbuf, MM, CC, EPAD, EPAD, EPAD, CC);
    gemm_mfma<1,1,1><<<gE, blk, 0, stream>>>(qb, kW1T, fbk, Hb, MM, EE, CC, CC, CC, EPAD);
    gemm_mfma<0,0,0><<<gC, blk, 0, stream>>>(Hb, kW2T, kb2, kbuf, MM, CC, EPAD, EPAD, EPAD, CC);
    gemm_mfma<1,1,1><<<gE, blk, 0, stream>>>(qb, vW1T, fbv, Hb, MM, EE, CC, CC, CC, EPAD);
    gemm_mfma<0,0,0><<<gC, blk, 0, stream>>>(Hb, vW2T, vb2, vbuf, MM, CC, EPAD, EPAD, EPAD, CC);

    // chunked recurrence (writes out into abuf, aliasing iclr)
    recurrence_chunked<<<dim3(BB * HH), dim3(512), 0, stream>>>(kbuf, abuf, dbuf, vbuf, rbuf,
                                                                rem_mult, iclr_mix, bonus_mult, abuf);

    // LN * gate -> bf16
    ln_gate_kernel<<<dim3(MM), blk, 0, stream>>>(abuf, gbuf, ln_g, ln_b, qb);

    // output MLP
    gemm_mfma<1,1,1><<<gE, blk, 0, stream>>>(qb, oW1T, ob1, Hb, MM, EE, CC, CC, CC, EPAD);
    gemm_mfma<0,0,0><<<gC, blk, 0, stream>>>(Hb, oW2T, ob2, out, MM, CC, EPAD, EPAD, EPAD, CC);
}

// Round 4
// 1247.254 us; speedup vs baseline: 8.0459x; 2.6703x over previous
//
#include <hip/hip_runtime.h>
#include <hip/hip_bf16.h>
#include <math.h>

// LinearAttentionLayerOptimized: B=4, T=2048, C=1024, H=16, N=64, L=128, E=1228
// Round 3: segment-parallel chunked recurrence (4 segs/seq, 128-step warm-up,
//          256 blocks) + two-pass deterministic bias folds + bf16 MFMA GEMMs.

#define BB 4
#define TT 2048
#define CC 1024
#define HH 16
#define NN 64
#define LL 128
#define EE 1228
#define EPAD 1280
#define MM (BB*TT)          // 8192 rows
#define TCH 32
#define NSEG 4              // segments per (b,h) sequence
#define WARMCH 4            // warm-up chunks (128 steps; decay<=0.82 -> ~1e-11)
#define DECAY_C_F 0.7408182206817179f

typedef __attribute__((ext_vector_type(8))) short s16x8;
typedef __attribute__((ext_vector_type(4))) float f32x4;

#define GLOAD_LDS16(gp, lp) \
    __builtin_amdgcn_global_load_lds((const __attribute__((address_space(1))) void*)(gp), \
                                     (__attribute__((address_space(3))) void*)(lp), 16, 0, 0)

// ---------------- two-pass bias folds (deterministic, parallel) ----------------
// pass1: partial[by*ldP + e] = sum_{c in [by*64,by*64+64)} mu[c] * W[c*ldW + e]
__global__ __launch_bounds__(256) void fold_pass1(const float* __restrict__ mu,
                                                  const float* __restrict__ W,
                                                  float* __restrict__ partial,
                                                  int ldW, int E, int ldP) {
    const int l = threadIdx.x & 63;
    const int e = blockIdx.x * 64 + l;
    const int pg = threadIdx.x >> 6;
    const int c0 = blockIdx.y * 64;
    float s = 0.f;
    if (e < E)
        for (int c = c0 + pg; c < c0 + 64; c += 4) s += mu[c] * W[(size_t)c * ldW + e];
    __shared__ float red[4][64];
    red[pg][l] = s;
    __syncthreads();
    if (pg == 0 && e < E)
        partial[(size_t)blockIdx.y * ldP + e] = red[0][l] + red[1][l] + red[2][l] + red[3][l];
}

// pass2: out[e] = (bias?bias[e]:0) + sum_{p<P} partial[p*ldP+e]
__global__ void fold_pass2(const float* __restrict__ partial, const float* __restrict__ bias,
                           float* __restrict__ outv, int P, int ldP, int E) {
    int e = blockIdx.x * blockDim.x + threadIdx.x;
    if (e >= E) return;
    float s = bias ? bias[e] : 0.f;
    for (int p = 0; p < P; ++p) s += partial[(size_t)p * ldP + e];
    outv[e] = s;
}

// ---------------- cast / transpose-cast ----------------
__global__ void cast_f32_bf16(const float* __restrict__ in, __hip_bfloat16* __restrict__ out, int n4) {
    int i = blockIdx.x * blockDim.x + threadIdx.x;
    if (i >= n4) return;
    float4 v = ((const float4*)in)[i];
    __hip_bfloat16 o[4] = {__float2bfloat16(v.x), __float2bfloat16(v.y),
                           __float2bfloat16(v.z), __float2bfloat16(v.w)};
    *(ulong1*)&out[i * 4] = *(ulong1*)o;
}

__global__ void transpose_cast(const float* __restrict__ in, __hip_bfloat16* __restrict__ outT,
                               int Rin, int Cin, int Rpad, int Cpad) {
    __shared__ float t[32][33];
    const int r0 = blockIdx.x * 32, c0 = blockIdx.y * 32;
    const int tx = threadIdx.x, ty = threadIdx.y;   // 32 x 8
    #pragma unroll
    for (int j = 0; j < 4; ++j) {
        int r = r0 + ty + j * 8, c = c0 + tx;
        t[ty + j * 8][tx] = (r < Rin && c < Cin) ? in[(size_t)r * Cin + c] : 0.f;
    }
    __syncthreads();
    #pragma unroll
    for (int j = 0; j < 4; ++j) {
        int c = c0 + ty + j * 8, r = r0 + tx;
        if (c < Cpad && r < Rpad) outT[(size_t)c * Rpad + r] = __float2bfloat16(t[tx][ty + j * 8]);
    }
}

// ---------------- bf16 MFMA GEMM ----------------
template<int ACT, int OBF, int PADZ>
__global__ __launch_bounds__(256) void gemm_mfma(const __hip_bfloat16* __restrict__ A,
                                                 const __hip_bfloat16* __restrict__ Bt,
                                                 const float* __restrict__ bias,
                                                 void* __restrict__ Cptr,
                                                 int M, int N, int K,
                                                 int ldA, int ldB, int ldC) {
    __shared__ __hip_bfloat16 As[128 * 32];
    __shared__ __hip_bfloat16 Bs[128 * 32];
    const int tid = threadIdx.x;
    const int wid = tid >> 6, lane = tid & 63;
    const int wm = wid >> 1, wn = wid & 1;
    const int bm = blockIdx.y * 128, bn = blockIdx.x * 128;

    const __hip_bfloat16* srcA[2];
    const __hip_bfloat16* srcB[2];
    #pragma unroll
    for (int i = 0; i < 2; ++i) {
        int off = (wid * 2 + i) * 1024 + lane * 16;
        int r = off >> 6;
        int c = (off >> 4) & 3;
        int cs = c ^ ((r >> 1) & 3);
        srcA[i] = A  + (size_t)(bm + r) * ldA + cs * 8;
        srcB[i] = Bt + (size_t)(bn + r) * ldB + cs * 8;
    }

    f32x4 acc[4][4];
    #pragma unroll
    for (int i = 0; i < 4; ++i)
        #pragma unroll
        for (int j = 0; j < 4; ++j) acc[i][j] = (f32x4){0.f, 0.f, 0.f, 0.f};

    for (int k0 = 0; k0 < K; k0 += 32) {
        #pragma unroll
        for (int i = 0; i < 2; ++i) {
            GLOAD_LDS16(srcA[i] + k0, (char*)As + (wid * 2 + i) * 1024);
            GLOAD_LDS16(srcB[i] + k0, (char*)Bs + (wid * 2 + i) * 1024);
        }
        __syncthreads();
        s16x8 af[4], bfr[4];
        #pragma unroll
        for (int mi = 0; mi < 4; ++mi) {
            int r = wm * 64 + mi * 16 + (lane & 15);
            int c = (lane >> 4) ^ ((r >> 1) & 3);
            af[mi] = *(const s16x8*)((const char*)As + r * 64 + c * 16);
        }
        #pragma unroll
        for (int ni = 0; ni < 4; ++ni) {
            int r = wn * 64 + ni * 16 + (lane & 15);
            int c = (lane >> 4) ^ ((r >> 1) & 3);
            bfr[ni] = *(const s16x8*)((const char*)Bs + r * 64 + c * 16);
        }
        #pragma unroll
        for (int mi = 0; mi < 4; ++mi)
            #pragma unroll
            for (int ni = 0; ni < 4; ++ni)
                acc[mi][ni] = __builtin_amdgcn_mfma_f32_16x16x32_bf16(af[mi], bfr[ni], acc[mi][ni], 0, 0, 0);
        __syncthreads();
    }

    #pragma unroll
    for (int ni = 0; ni < 4; ++ni) {
        const int col = bn + wn * 64 + ni * 16 + (lane & 15);
        const bool valid = (col < N);
        const float bc = (valid && bias) ? bias[col] : 0.f;
        #pragma unroll
        for (int mi = 0; mi < 4; ++mi) {
            #pragma unroll
            for (int reg = 0; reg < 4; ++reg) {
                const int row = bm + wm * 64 + mi * 16 + (lane >> 4) * 4 + reg;
                float y = 0.f;
                if (valid) {
                    float x = acc[mi][ni][reg] + bc;
                    if (ACT == 1)      y = 0.5f * x * (1.0f + erff(x * 0.7071067811865475f));
                    else if (ACT == 2) y = 1.0f / (1.0f + expf(-x));
                    else if (ACT == 3) { float sg = 1.0f / (1.0f + expf(-tanhf(x))); y = expf(-DECAY_C_F * sg); }
                    else               y = x;
                }
                if (valid || PADZ) {
                    if (OBF) ((__hip_bfloat16*)Cptr)[(size_t)row * ldC + col] = __float2bfloat16(y);
                    else     ((float*)Cptr)[(size_t)row * ldC + col] = y;
                }
            }
        }
    }
}

// ---------------- segment-parallel chunked recurrence ----------------
// grid = 64 bh * NSEG segments. Each segment: warm-up WARMCH chunks from T0=0
// (valid because per-step decay <= 0.82 -> 0.82^128 ~ 1e-11), then 16 output chunks.
// Output buffer is DISJOINT from iclr (segments read iclr rows other segments write).
#define P_T0(i,j)   pool[0     + (i)*68 + (j)]
#define P_WT(i,j)   pool[4352  + (i)*68 + (j)]
#define P_KP(i,j)   pool[6528  + (i)*68 + (j)]
#define P_P2t(i,j)  pool[6528  + (i)*36 + (j)]   // aliases KP (dead after phase2)
#define P_NU(i,j)   pool[8704  + (i)*68 + (j)]
#define P_GRt(i,j)  pool[8704  + (i)*36 + (j)]   // aliases NU (dead after phase2)
#define P_RKM(i,j)  pool[10880 + (i)*68 + (j)]
#define P_RRM(i,j)  pool[13056 + (i)*68 + (j)]
#define P_GM(i,j)   pool[15232 + (i)*68 + (j)]
#define P_GMT(i,j)  pool[17408 + (i)*36 + (j)]
#define P_KPT(i,j)  pool[19712 + (i)*36 + (j)]
#define P_NUT(i,j)  pool[22016 + (i)*36 + (j)]
#define P_RKMT(i,j) pool[24320 + (i)*36 + (j)]
#define P_DCT(i,j)  pool[26624 + (i)*36 + (j)]
#define P_AT(i,j)   pool[28928 + (i)*36 + (j)]
#define P_BM(i,j)   pool[30080 + (i)*36 + (j)]
#define P_SEG(i,j)  pool[31232 + (i)*64 + (j)]
#define LD4(expr)   (*(const float4*)&(expr))

__global__ __launch_bounds__(512) void recurrence_chunked(
    const float* __restrict__ kbuf, const float* __restrict__ iclr,
    const float* __restrict__ dbuf, const float* __restrict__ vbuf,
    const float* __restrict__ rbuf,
    const float* __restrict__ rem_mult, const float* __restrict__ iclr_mix,
    const float* __restrict__ bonus_mult, float* __restrict__ outb) {
    __shared__ float pool[31488];   // 123 KB
    const int bh = blockIdx.x & 63, seg = blockIdx.x >> 6;
    const int b = bh >> 4, h = bh & 15;
    const int tid = threadIdx.x, lane = tid & 63, wid = tid >> 6;
    const size_t gbase = ((size_t)b * TT) * CC + (size_t)h * NN;

    for (int i = tid; i < 4352; i += 512) pool[i] = 0.f;   // T0 = 0 at segment start
    const int c0 = tid & 63;
    const float remc = rem_mult[h * NN + c0];
    const float mixc = iclr_mix[h * NN + c0];
    __syncthreads();

    const int cout0 = seg * (TT / TCH / NSEG);             // first output chunk
    const int cb = (seg == 0) ? 0 : cout0 - WARMCH;
    const int ce = cout0 + (TT / TCH / NSEG);

    for (int chk = cb; chk < ce; ++chk) {
        const bool emit = (chk >= cout0);
        const int tg0 = chk * TCH;
        // ---- load & elementwise ----
        #pragma unroll
        for (int i = 0; i < 4; ++i) {
            int idx = tid + 512 * i;
            int t = idx >> 6, c = idx & 63;
            size_t off = gbase + (size_t)(tg0 + t) * CC + c;
            float kx = kbuf[off], ax = iclr[off];
            float rk = kx * (1.f + (ax - 1.f) * mixc);
            P_WT(t, c) = ax;
            P_KP(t, c) = kx * remc;
            P_RKM(t, c) = rk; P_RKMT(c, t) = rk;
            P_NU(t, c) = vbuf[off];
            if (emit) P_RRM(t, c) = rbuf[off];
            P_DCT(c, t) = dbuf[off];
        }
        __syncthreads();
        // ---- row norms ----
        #pragma unroll
        for (int rr = 0; rr < 4; ++rr) {
            int t = wid + rr * 8;
            float v = P_KP(t, lane);
            float ss = v * v;
            #pragma unroll
            for (int s = 32; s; s >>= 1) ss += __shfl_xor(ss, s);
            float kn = v / fmaxf(sqrtf(ss), 1e-12f);
            P_KP(t, lane) = kn;
            P_WT(t, lane) = P_WT(t, lane) * kn;
        }
        __syncthreads();
        // ---- segmented cumprod + scaled quantities ----
        float lc[8];
        int ccs = tid & 63, sgm = tid >> 6, t0s = sgm * 8;
        if (tid < 256) {
            float pp = 1.f;
            #pragma unroll
            for (int j = 0; j < 8; ++j) { pp *= P_DCT(ccs, t0s + j); lc[j] = pp; }
            P_SEG(sgm, ccs) = pp;
        }
        __syncthreads();
        if (tid < 256) {
            float m = 1.f;
            for (int s = 0; s < sgm; ++s) m *= P_SEG(s, ccs);
            float dcprev = m;
            #pragma unroll
            for (int j = 0; j < 8; ++j) {
                int t = t0s + j;
                float dcur = m * lc[j];
                P_WT(t, ccs) *= dcprev;
                float inv = 1.f / dcur;
                float kap = P_KP(t, ccs) * inv; P_KP(t, ccs) = kap; P_KPT(ccs, t) = kap;
                float nu  = P_NU(t, ccs) * inv; P_NU(t, ccs) = nu;  P_NUT(ccs, t) = nu;
                P_DCT(ccs, t) = dcur;
                dcprev = dcur;
            }
        }
        __syncthreads();
        // ---- phase2: AT, BM, WT.T0 -> GM ----
        for (int tile = wid; tile < 64; tile += 8) {
            if (tile < 16) {
                int s = (tile >> 2) * 8 + (lane >> 3), t = (tile & 3) * 8 + (lane & 7);
                float acc = 0.f;
                #pragma unroll
                for (int kc = 0; kc < 16; ++kc) {
                    float4 a = LD4(P_KP(s, kc * 4));
                    float4 bb = LD4(P_WT(t, kc * 4));
                    acc += a.x * bb.x + a.y * bb.y + a.z * bb.z + a.w * bb.w;
                }
                P_AT(s, t) = (s < t) ? acc : 0.f;
            } else if (tile < 32) {
                int t = ((tile - 16) >> 2) * 8 + (lane >> 3), s = ((tile - 16) & 3) * 8 + (lane & 7);
                float acc = 0.f;
                #pragma unroll
                for (int kc = 0; kc < 16; ++kc) {
                    float4 a = LD4(P_WT(t, kc * 4));
                    float4 bb = LD4(P_NU(s, kc * 4));
                    acc += a.x * bb.x + a.y * bb.y + a.z * bb.z + a.w * bb.w;
                }
                P_BM(t, s) = (s < t) ? acc : 0.f;
            } else {
                int tt = tile - 32;
                int t = (tt >> 3) * 8 + (lane >> 3), q = (tt & 7) * 8 + (lane & 7);
                float acc = 0.f;
                #pragma unroll
                for (int j4 = 0; j4 < 16; ++j4) {
                    float4 a = LD4(P_WT(t, j4 * 4));
                    acc += a.x * P_T0(j4 * 4 + 0, q) + a.y * P_T0(j4 * 4 + 1, q)
                         + a.z * P_T0(j4 * 4 + 2, q) + a.w * P_T0(j4 * 4 + 3, q);
                }
                P_GM(t, q) = acc;
            }
        }
        __syncthreads();
        // ---- phase3: GM += BM . RKM ----
        for (int tile = wid; tile < 32; tile += 8) {
            int t = (tile >> 3) * 8 + (lane >> 3), q = (tile & 7) * 8 + (lane & 7);
            float acc = 0.f;
            #pragma unroll
            for (int s4 = 0; s4 < 8; ++s4) {
                float4 a = LD4(P_BM(t, s4 * 4));
                acc += a.x * P_RKM(s4 * 4 + 0, q) + a.y * P_RKM(s4 * 4 + 1, q)
                     + a.z * P_RKM(s4 * 4 + 2, q) + a.w * P_RKM(s4 * 4 + 3, q);
            }
            P_GM(t, q) += acc;
        }
        __syncthreads();
        // ---- phase4: wave0 solve || waves1-7 P2t (emit only) ----
        if (wid == 0) {
            float g[32];
            #pragma unroll
            for (int t = 0; t < 32; ++t) g[t] = P_GM(t, lane);
            #pragma unroll
            for (int s = 0; s < 31; ++s) {
                #pragma unroll
                for (int t = s + 1; t < 32; ++t) g[t] -= P_AT(s, t) * g[s];
            }
            #pragma unroll
            for (int t = 0; t < 32; ++t) { P_GM(t, lane) = g[t]; P_GMT(lane, t) = g[t]; }
        } else if (emit) {
            for (int tile = wid - 1; tile < 16; tile += 7) {
                int t = (tile >> 2) * 8 + (lane >> 3), s = (tile & 3) * 8 + (lane & 7);
                float acc = 0.f;
                #pragma unroll
                for (int kc = 0; kc < 16; ++kc) {
                    float4 a = LD4(P_RRM(t, kc * 4));
                    float4 bb = LD4(P_RKM(s, kc * 4));
                    acc += a.x * bb.x + a.y * bb.y + a.z * bb.z + a.w * bb.w;
                }
                P_P2t(t, s) = (s <= t) ? acc : 0.f;
            }
        }
        __syncthreads();
        if (emit) {
            // ---- phase5: GRt[t][s] = g_s . r_t ----
            for (int tile = wid; tile < 16; tile += 8) {
                int t = (tile >> 2) * 8 + (lane >> 3), s = (tile & 3) * 8 + (lane & 7);
                float acc = 0.f;
                #pragma unroll
                for (int kc = 0; kc < 16; ++kc) {
                    float4 a = LD4(P_RRM(t, kc * 4));
                    float4 bb = LD4(P_GM(s, kc * 4));
                    acc += a.x * bb.x + a.y * bb.y + a.z * bb.z + a.w * bb.w;
                }
                P_GRt(t, s) = (s <= t) ? acc : 0.f;
            }
            __syncthreads();
            // ---- phase6a: outputs ----
            for (int tile = wid; tile < 32; tile += 8) {
                int i = (tile >> 2) * 8 + (lane >> 3), t = (tile & 3) * 8 + (lane & 7);
                float a1 = 0.f, a2 = 0.f, a3 = 0.f;
                #pragma unroll
                for (int j4 = 0; j4 < 16; ++j4) {
                    float4 a = LD4(P_T0(i, j4 * 4));
                    float4 bb = LD4(P_RRM(t, j4 * 4));
                    a1 += a.x * bb.x + a.y * bb.y + a.z * bb.z + a.w * bb.w;
                }
                #pragma unroll
                for (int s4 = 0; s4 < 8; ++s4) {
                    float4 a = LD4(P_NUT(i, s4 * 4));
                    float4 bb = LD4(P_P2t(t, s4 * 4));
                    a2 += a.x * bb.x + a.y * bb.y + a.z * bb.z + a.w * bb.w;
                    float4 c = LD4(P_KPT(i, s4 * 4));
                    float4 d = LD4(P_GRt(t, s4 * 4));
                    a3 += c.x * d.x + c.y * d.y + c.z * d.z + c.w * d.w;
                }
                float diag = 0.2f * bonus_mult[h * NN + i] * P_NUT(i, t) * P_P2t(t, t);
                outb[gbase + (size_t)(tg0 + t) * CC + i] = P_DCT(i, t) * (a1 + a2 + diag - a3);
            }
            __syncthreads();
        }
        // ---- phase6b: T0 <- dc_end * (T0 - Kap^T G + Nu^T RK) ----
        for (int tile = wid; tile < 64; tile += 8) {
            int pr = (tile >> 3) * 8 + (lane >> 3), q = (tile & 7) * 8 + (lane & 7);
            float a1 = 0.f, a2 = 0.f;
            #pragma unroll
            for (int s4 = 0; s4 < 8; ++s4) {
                float4 a = LD4(P_KPT(pr, s4 * 4));
                float4 bb = LD4(P_GMT(q, s4 * 4));
                a1 += a.x * bb.x + a.y * bb.y + a.z * bb.z + a.w * bb.w;
                float4 c = LD4(P_NUT(pr, s4 * 4));
                float4 d = LD4(P_RKMT(q, s4 * 4));
                a2 += c.x * d.x + c.y * d.y + c.z * d.z + c.w * d.w;
            }
            P_T0(pr, q) = P_DCT(pr, 31) * (P_T0(pr, q) - a1 + a2);
        }
        __syncthreads();
    }
}

// ---------------- LayerNorm * gate (bf16 out) ----------------
__global__ __launch_bounds__(256) void ln_gate_kernel(const float* __restrict__ x,
                                                      const __hip_bfloat16* __restrict__ gate,
                                                      const float* __restrict__ g,
                                                      const float* __restrict__ bv,
                                                      __hip_bfloat16* __restrict__ y) {
    const int row = blockIdx.x;
    const float* xr = x + (size_t)row * CC;
    float v[4];
    float s = 0.f;
    #pragma unroll
    for (int j = 0; j < 4; ++j) { v[j] = xr[threadIdx.x + 256 * j]; s += v[j]; }
    __shared__ float red[4], red2[4];
    #pragma unroll
    for (int o = 32; o; o >>= 1) s += __shfl_xor(s, o);
    if ((threadIdx.x & 63) == 0) red[threadIdx.x >> 6] = s;
    __syncthreads();
    const float mean = (red[0] + red[1] + red[2] + red[3]) * (1.f / CC);
    float vs = 0.f;
    #pragma unroll
    for (int j = 0; j < 4; ++j) { float d = v[j] - mean; vs += d * d; }
    #pragma unroll
    for (int o = 32; o; o >>= 1) vs += __shfl_xor(vs, o);
    if ((threadIdx.x & 63) == 0) red2[threadIdx.x >> 6] = vs;
    __syncthreads();
    const float var = (red2[0] + red2[1] + red2[2] + red2[3]) * (1.f / CC);
    const float rstd = rsqrtf(var + 1e-6f);
    #pragma unroll
    for (int j = 0; j < 4; ++j) {
        const int cc = threadIdx.x + 256 * j;
        float o_ = (v[j] - mean) * rstd * g[cc] + bv[cc];
        float gt = __bfloat162float(gate[(size_t)row * CC + cc]);
        y[(size_t)row * CC + cc] = __float2bfloat16(o_ * gt);
    }
}

// ---------------- launch ----------------
extern "C" void kernel_launch(void* const* d_in, const int* in_sizes, int n_in,
                              void* d_out, int out_size, void* d_ws, size_t ws_size,
                              hipStream_t stream) {
    const float* q        = (const float*)d_in[0];
    const float* mu_r     = (const float*)d_in[4];
    const float* mu_k     = (const float*)d_in[5];
    const float* mu_v     = (const float*)d_in[6];
    const float* mu_g     = (const float*)d_in[7];
    const float* mu_a     = (const float*)d_in[8];
    const float* mu_d     = (const float*)d_in[9];
    const float* dA       = (const float*)d_in[10];
    const float* dB       = (const float*)d_in[11];
    const float* db       = (const float*)d_in[12];
    const float* aA       = (const float*)d_in[13];
    const float* aB       = (const float*)d_in[14];
    const float* ab       = (const float*)d_in[15];
    const float* gA       = (const float*)d_in[16];
    const float* gB       = (const float*)d_in[17];
    const float* rW1      = (const float*)d_in[18];
    const float* rb1      = (const float*)d_in[19];
    const float* rW2      = (const float*)d_in[20];
    const float* rb2      = (const float*)d_in[21];
    const float* kW1      = (const float*)d_in[22];
    const float* kb1      = (const float*)d_in[23];
    const float* kW2      = (const float*)d_in[24];
    const float* kb2      = (const float*)d_in[25];
    const float* vW1      = (const float*)d_in[26];
    const float* vb1      = (const float*)d_in[27];
    const float* vW2      = (const float*)d_in[28];
    const float* vb2      = (const float*)d_in[29];
    const float* oW1      = (const float*)d_in[30];
    const float* ob1      = (const float*)d_in[31];
    const float* oW2      = (const float*)d_in[32];
    const float* ob2      = (const float*)d_in[33];
    const float* rem_mult = (const float*)d_in[34];
    const float* iclr_mix = (const float*)d_in[35];
    const float* bonus_mult = (const float*)d_in[36];
    const float* ln_g     = (const float*)d_in[37];
    const float* ln_b     = (const float*)d_in[38];
    float* out = (float*)d_out;

    // ---- workspace arena ----
    char* p = (char*)d_ws;
    auto alloc = [&](size_t bytes) { char* r = p; p += (bytes + 255) & ~(size_t)255; return r; };
    float* fbr = (float*)alloc(EPAD * 4);
    float* fbk = (float*)alloc(EPAD * 4);
    float* fbv = (float*)alloc(EPAD * 4);
    float* cg2 = (float*)alloc(CC * 4);
    float* ca2 = (float*)alloc(CC * 4);
    float* cd2 = (float*)alloc(CC * 4);
    float* lt  = (float*)alloc(LL * 4);
    float* pp  = (float*)alloc((size_t)16 * EPAD * 4);   // fold partials
    __hip_bfloat16* qb   = (__hip_bfloat16*)alloc((size_t)MM * CC * 2);   // also ln_out later
    __hip_bfloat16* rW1T = (__hip_bfloat16*)alloc((size_t)EPAD * CC * 2);
    __hip_bfloat16* kW1T = (__hip_bfloat16*)alloc((size_t)EPAD * CC * 2);
    __hip_bfloat16* vW1T = (__hip_bfloat16*)alloc((size_t)EPAD * CC * 2);
    __hip_bfloat16* oW1T = (__hip_bfloat16*)alloc((size_t)EPAD * CC * 2);
    __hip_bfloat16* rW2T = (__hip_bfloat16*)alloc((size_t)CC * EPAD * 2);
    __hip_bfloat16* kW2T = (__hip_bfloat16*)alloc((size_t)CC * EPAD * 2);
    __hip_bfloat16* vW2T = (__hip_bfloat16*)alloc((size_t)CC * EPAD * 2);
    __hip_bfloat16* oW2T = (__hip_bfloat16*)alloc((size_t)CC * EPAD * 2);
    __hip_bfloat16* gAT  = (__hip_bfloat16*)alloc((size_t)LL * CC * 2);
    __hip_bfloat16* aAT  = (__hip_bfloat16*)alloc((size_t)LL * CC * 2);
    __hip_bfloat16* dAT  = (__hip_bfloat16*)alloc((size_t)LL * CC * 2);
    __hip_bfloat16* gBT  = (__hip_bfloat16*)alloc((size_t)CC * LL * 2);
    __hip_bfloat16* aBT  = (__hip_bfloat16*)alloc((size_t)CC * LL * 2);
    __hip_bfloat16* dBT  = (__hip_bfloat16*)alloc((size_t)CC * LL * 2);
    __hip_bfloat16* Hb   = (__hip_bfloat16*)alloc((size_t)MM * EPAD * 2);
    __hip_bfloat16* tg   = Hb;                       // LoRA intermediates alias Hb
    __hip_bfloat16* ta   = Hb + (size_t)MM * LL;
    __hip_bfloat16* td   = Hb + (size_t)2 * MM * LL;
    float* rbuf = (float*)alloc((size_t)MM * CC * 4);
    float* kbuf = (float*)alloc((size_t)MM * CC * 4);
    float* vbuf = (float*)alloc((size_t)MM * CC * 4);
    float* abuf = (float*)alloc((size_t)MM * CC * 4);   // iclr (read-only after LoRA)
    float* dbuf = (float*)alloc((size_t)MM * CC * 4);   // decay f32
    __hip_bfloat16* gbuf = (__hip_bfloat16*)alloc((size_t)MM * CC * 2);

    const dim3 blk(256);
    const dim3 tblk(32, 8);

    // casts & transposes
    cast_f32_bf16<<<dim3((MM * CC / 4 + 255) / 256), blk, 0, stream>>>(q, qb, MM * CC / 4);
    transpose_cast<<<dim3(32, 40), tblk, 0, stream>>>(rW1, rW1T, CC, EE, CC, EPAD);
    transpose_cast<<<dim3(32, 40), tblk, 0, stream>>>(kW1, kW1T, CC, EE, CC, EPAD);
    transpose_cast<<<dim3(32, 40), tblk, 0, stream>>>(vW1, vW1T, CC, EE, CC, EPAD);
    transpose_cast<<<dim3(32, 40), tblk, 0, stream>>>(oW1, oW1T, CC, EE, CC, EPAD);
    transpose_cast<<<dim3(40, 32), tblk, 0, stream>>>(rW2, rW2T, EE, CC, EPAD, CC);
    transpose_cast<<<dim3(40, 32), tblk, 0, stream>>>(kW2, kW2T, EE, CC, EPAD, CC);
    transpose_cast<<<dim3(40, 32), tblk, 0, stream>>>(vW2, vW2T, EE, CC, EPAD, CC);
    transpose_cast<<<dim3(40, 32), tblk, 0, stream>>>(oW2, oW2T, EE, CC, EPAD, CC);
    transpose_cast<<<dim3(32, 4), tblk, 0, stream>>>(gA, gAT, CC, LL, CC, LL);
    transpose_cast<<<dim3(32, 4), tblk, 0, stream>>>(aA, aAT, CC, LL, CC, LL);
    transpose_cast<<<dim3(32, 4), tblk, 0, stream>>>(dA, dAT, CC, LL, CC, LL);
    transpose_cast<<<dim3(4, 32), tblk, 0, stream>>>(gB, gBT, LL, CC, LL, CC);
    transpose_cast<<<dim3(4, 32), tblk, 0, stream>>>(aB, aBT, LL, CC, LL, CC);
    transpose_cast<<<dim3(4, 32), tblk, 0, stream>>>(dB, dBT, LL, CC, LL, CC);

    // bias folds (two-pass, deterministic)
    fold_pass1<<<dim3(20, 16), blk, 0, stream>>>(mu_r, rW1, pp, EE, EE, EPAD);
    fold_pass2<<<dim3(5), blk, 0, stream>>>(pp, rb1, fbr, 16, EPAD, EE);
    fold_pass1<<<dim3(20, 16), blk, 0, stream>>>(mu_k, kW1, pp, EE, EE, EPAD);
    fold_pass2<<<dim3(5), blk, 0, stream>>>(pp, kb1, fbk, 16, EPAD, EE);
    fold_pass1<<<dim3(20, 16), blk, 0, stream>>>(mu_v, vW1, pp, EE, EE, EPAD);
    fold_pass2<<<dim3(5), blk, 0, stream>>>(pp, vb1, fbv, 16, EPAD, EE);
    fold_pass1<<<dim3(2, 16), blk, 0, stream>>>(mu_g, gA, pp, LL, LL, EPAD);
    fold_pass2<<<dim3(1), dim3(128), 0, stream>>>(pp, nullptr, lt, 16, EPAD, LL);
    fold_pass1<<<dim3(16, 2), blk, 0, stream>>>(lt, gB, pp, CC, CC, EPAD);
    fold_pass2<<<dim3(4), blk, 0, stream>>>(pp, nullptr, cg2, 2, EPAD, CC);
    fold_pass1<<<dim3(2, 16), blk, 0, stream>>>(mu_a, aA, pp, LL, LL, EPAD);
    fold_pass2<<<dim3(1), dim3(128), 0, stream>>>(pp, nullptr, lt, 16, EPAD, LL);
    fold_pass1<<<dim3(16, 2), blk, 0, stream>>>(lt, aB, pp, CC, CC, EPAD);
    fold_pass2<<<dim3(4), blk, 0, stream>>>(pp, ab, ca2, 2, EPAD, CC);
    fold_pass1<<<dim3(2, 16), blk, 0, stream>>>(mu_d, dA, pp, LL, LL, EPAD);
    fold_pass2<<<dim3(1), dim3(128), 0, stream>>>(pp, nullptr, lt, 16, EPAD, LL);
    fold_pass1<<<dim3(16, 2), blk, 0, stream>>>(lt, dB, pp, CC, CC, EPAD);
    fold_pass2<<<dim3(4), blk, 0, stream>>>(pp, db, cd2, 2, EPAD, CC);

    const dim3 gLA(1, MM / 128);          // N=128
    const dim3 gC(CC / 128, MM / 128);    // N=1024
    const dim3 gE(EPAD / 128, MM / 128);  // N=1228 -> 1280

    // LoRA A-stage
    gemm_mfma<0,1,0><<<gLA, blk, 0, stream>>>(qb, gAT, nullptr, tg, MM, LL, CC, CC, CC, LL);
    gemm_mfma<0,1,0><<<gLA, blk, 0, stream>>>(qb, aAT, nullptr, ta, MM, LL, CC, CC, CC, LL);
    gemm_mfma<0,1,0><<<gLA, blk, 0, stream>>>(qb, dAT, nullptr, td, MM, LL, CC, CC, CC, LL);
    // LoRA B-stage
    gemm_mfma<2,1,0><<<gC, blk, 0, stream>>>(tg, gBT, cg2, gbuf, MM, CC, LL, LL, LL, CC);
    gemm_mfma<2,0,0><<<gC, blk, 0, stream>>>(ta, aBT, ca2, abuf, MM, CC, LL, LL, LL, CC);
    gemm_mfma<3,0,0><<<gC, blk, 0, stream>>>(td, dBT, cd2, dbuf, MM, CC, LL, LL, LL, CC);

    // MLPs r/k/v
    gemm_mfma<1,1,1><<<gE, blk, 0, stream>>>(qb, rW1T, fbr, Hb, MM, EE, CC, CC, CC, EPAD);
    gemm_mfma<0,0,0><<<gC, blk, 0, stream>>>(Hb, rW2T, rb2, rbuf, MM, CC, EPAD, EPAD, EPAD, CC);
    gemm_mfma<1,1,1><<<gE, blk, 0, stream>>>(qb, kW1T, fbk, Hb, MM, EE, CC, CC, CC, EPAD);
    gemm_mfma<0,0,0><<<gC, blk, 0, stream>>>(Hb, kW2T, kb2, kbuf, MM, CC, EPAD, EPAD, EPAD, CC);
    gemm_mfma<1,1,1><<<gE, blk, 0, stream>>>(qb, vW1T, fbv, Hb, MM, EE, CC, CC, CC, EPAD);
    gemm_mfma<0,0,0><<<gC, blk, 0, stream>>>(Hb, vW2T, vb2, vbuf, MM, CC, EPAD, EPAD, EPAD, CC);

    // segment-parallel chunked recurrence -> writes d_out (fp32 scratch here)
    recurrence_chunked<<<dim3(BB * HH * NSEG), dim3(512), 0, stream>>>(
        kbuf, abuf, dbuf, vbuf, rbuf, rem_mult, iclr_mix, bonus_mult, out);

    // LN * gate -> bf16 (reads d_out scratch, writes qb)
    ln_gate_kernel<<<dim3(MM), blk, 0, stream>>>(out, gbuf, ln_g, ln_b, qb);

    // output MLP (overwrites d_out with final result)
    gemm_mfma<1,1,1><<<gE, blk, 0, stream>>>(qb, oW1T, ob1, Hb, MM, EE, CC, CC, CC, EPAD);
    gemm_mfma<0,0,0><<<gC, blk, 0, stream>>>(Hb, oW2T, ob2, out, MM, CC, EPAD, EPAD, EPAD, CC);
}